// Round 8
// baseline (962.422 us; speedup 1.0000x reference)
//
#include <hip/hip_runtime.h>
#include <cmath>

#define EPSBN 1e-5f

typedef __attribute__((ext_vector_type(8))) short short8v;
typedef __attribute__((ext_vector_type(4))) short short4v;
typedef __attribute__((ext_vector_type(4))) float f32x4;

__device__ inline unsigned short f2b(float x) {
  union { float f; unsigned int u; } v; v.f = x;
  unsigned int b = v.u;
  return (unsigned short)((b + 0x7FFFu + ((b >> 16) & 1u)) >> 16);
}
__device__ inline float b2f(unsigned short x) {
  union { unsigned int u; float f; } v; v.u = ((unsigned int)x) << 16;
  return v.f;
}

// ---------------- fused weight prep + zero-init ----------------
__global__ __launch_bounds__(256) void k_wprep(const float* __restrict__ W_g, const float* __restrict__ W_ih,
                                               const float* __restrict__ W_hh, const float* __restrict__ W_in,
                                               const float* __restrict__ W1, const float* __restrict__ b_ih,
                                               unsigned short* __restrict__ fusedBT, unsigned short* __restrict__ BThh,
                                               unsigned short* __restrict__ BTin, unsigned short* __restrict__ BT1,
                                               float* __restrict__ fbias, float* __restrict__ stats,
                                               int* __restrict__ degi, int N) {
  int i = blockIdx.x * 256 + threadIdx.x;
  if (i < 16384) {
    int k = i >> 7, m = i & 127;
    fusedBT[m * 128 + k] = f2b(W_g[i]);
  } else if (i < 65536) {
    int j = i - 16384;
    fusedBT[16384 + j] = f2b(W_ih[j]);
  } else if (i < 114688) {
    int j = i - 65536;
    BThh[j] = f2b(W_hh[j]);
  } else if (i < 131072) {
    int j = i - 114688;
    int k = j >> 7, m = j & 127;
    BTin[m * 128 + k] = f2b(W_in[j]);
  } else if (i < 163840) {
    int j = i - 131072;
    int k = j >> 8, m = j & 255;
    BT1[m * 128 + k] = f2b(W1[j]);
  } else if (i < 164352) {
    int j = i - 163840;
    fbias[j] = (j < 128) ? 0.f : b_ih[j - 128];
  } else if (i < 168456) {
    stats[i - 164352] = 0.f;   // 8*512 stats + 8 counters
  } else if (i < 168456 + N) {
    degi[i - 168456] = 0;
  }
}

// ---------------- graph preprocessing ----------------
__global__ __launch_bounds__(256) void k_count_deg(const int* __restrict__ dst, int* __restrict__ deg, int E) {
  int i = blockIdx.x * 256 + threadIdx.x;
  if (i < E) atomicAdd(&deg[dst[i]], 1);
}

__global__ __launch_bounds__(256) void k_scan_p1(const int* __restrict__ deg, int* __restrict__ rowptr,
                                                 int* __restrict__ bsum, float* __restrict__ dis, int N) {
  __shared__ int sd[256];
  int t = threadIdx.x;
  int i = blockIdx.x * 256 + t;
  int v = (i < N) ? deg[i] : 0;
  if (i < N) dis[i] = rsqrtf((float)(v + 1));
  sd[t] = v;
  __syncthreads();
  for (int off = 1; off < 256; off <<= 1) {
    int u = (t >= off) ? sd[t - off] : 0;
    __syncthreads();
    sd[t] += u;
    __syncthreads();
  }
  if (i < N) rowptr[i] = sd[t] - v;
  if (t == 255) bsum[blockIdx.x] = sd[255];
}

__global__ void k_scan_p2(int* __restrict__ bsum, int NBLK) {
  __shared__ int sd[256];
  int t = threadIdx.x;
  int v = (t < NBLK) ? bsum[t] : 0;
  sd[t] = v;
  __syncthreads();
  for (int off = 1; off < 256; off <<= 1) {
    int u = (t >= off) ? sd[t - off] : 0;
    __syncthreads();
    sd[t] += u;
    __syncthreads();
  }
  if (t < NBLK) bsum[t] = sd[t] - v;
}

__global__ __launch_bounds__(256) void k_scan_p3(int* __restrict__ rowptr, int* __restrict__ cursor,
                                                 const int* __restrict__ bsum, int N, int E) {
  int i = blockIdx.x * 256 + threadIdx.x;
  if (i < N) {
    int v = rowptr[i] + bsum[blockIdx.x];
    rowptr[i] = v;
    cursor[i] = v;
  } else if (i == N) {
    rowptr[N] = E;
  }
}

__global__ __launch_bounds__(256) void k_csr_fill(const int* __restrict__ src, const int* __restrict__ dst,
                                                  int* __restrict__ cursor, int* __restrict__ csr_src, int E) {
  int e = blockIdx.x * 256 + threadIdx.x;
  if (e >= E) return;
  int s = src[e], d = dst[e];
  int pos = atomicAdd(&cursor[d], 1);
  csr_src[pos] = s;
}

// ---------------- bf16 MFMA matmul (see r7 comments) ----------------
template<int ABF, int STATS, int SPLIT, int OBF, int BNA, int MXW, int FIN>
__global__ __launch_bounds__(256) void k_mmx(const void* __restrict__ Ap, const unsigned short* __restrict__ BT,
                                             const float* __restrict__ bias,
                                             void* __restrict__ Co, unsigned short* __restrict__ Csplit,
                                             const float* __restrict__ coefA, unsigned short* __restrict__ mxp,
                                             float* __restrict__ psum, float* __restrict__ psqs,
                                             const float* __restrict__ gamma, const float* __restrict__ beta,
                                             float* __restrict__ coefOut, int* __restrict__ cnt,
                                             float invN, int D,
                                             int N, int ldA, int ldC, int relu)
{
  __shared__ unsigned short As[128 * 128];
  __shared__ unsigned short Bs[128 * 128];
  char* Asb = (char*)As;
  char* Bsb = (char*)Bs;
  int tid = threadIdx.x;
  int brow = blockIdx.y * 128, bcol = blockIdx.x * 128;

#pragma unroll
  for (int p = 0; p < 8; ++p) {
    int idx = p * 256 + tid;
    int r = idx >> 4, ch = idx & 15;
    int arow = brow + r;
    float fv[8];
    if (ABF) {
      short8v raw = {0, 0, 0, 0, 0, 0, 0, 0};
      if (arow < N) raw = *(const short8v*)((const unsigned short*)Ap + (size_t)arow * ldA + ch * 8);
#pragma unroll
      for (int j = 0; j < 8; ++j) fv[j] = b2f((unsigned short)raw[j]);
    } else {
      if (arow < N) {
        const float* a = (const float*)Ap + (size_t)arow * ldA + ch * 8;
        f32x4 x0 = *(const f32x4*)a;
        f32x4 x1 = *(const f32x4*)(a + 4);
        fv[0] = x0[0]; fv[1] = x0[1]; fv[2] = x0[2]; fv[3] = x0[3];
        fv[4] = x1[0]; fv[5] = x1[1]; fv[6] = x1[2]; fv[7] = x1[3];
      } else {
#pragma unroll
        for (int j = 0; j < 8; ++j) fv[j] = 0.f;
      }
    }
    if (BNA) {
#pragma unroll
      for (int j = 0; j < 8; ++j) {
        int k = ch * 8 + j;
        fv[j] = fv[j] * coefA[k] + coefA[128 + k];
      }
    }
    if (MXW) {
      if (blockIdx.x == 0 && arow < N) {
        size_t mi = (size_t)arow * 128 + ch * 8;
        short8v mo;
        if (MXW == 2) mo = *(const short8v*)(mxp + mi);
        short8v mn;
#pragma unroll
        for (int j = 0; j < 8; ++j) {
          float w = fv[j];
          if (MXW == 2) w = fmaxf(b2f((unsigned short)mo[j]), w);
          mn[j] = (short)f2b(w);
        }
        *(short8v*)(mxp + mi) = mn;
      }
    }
    short8v v;
#pragma unroll
    for (int j = 0; j < 8; ++j) v[j] = (short)f2b(fv[j]);
    *(short8v*)(Asb + r * 256 + ((ch * 16) ^ ((r & 7) << 4))) = v;
  }
#pragma unroll
  for (int p = 0; p < 8; ++p) {
    int idx = p * 256 + tid;
    int r = idx >> 4, ch = idx & 15;
    short8v v = *(const short8v*)(BT + (size_t)(bcol + r) * 128 + ch * 8);
    *(short8v*)(Bsb + r * 256 + ((ch * 16) ^ ((r & 7) << 4))) = v;
  }
  __syncthreads();

  int w = tid >> 6, l = tid & 63;
  int wm = (w >> 1) * 64, wn = (w & 1) * 64;
  int lg = l >> 4, lr = l & 15;
  f32x4 acc[4][4] = {};

#pragma unroll
  for (int ks = 0; ks < 4; ++ks) {
    int kb = ks * 64 + lg * 8;
    short8v a[4], b[4];
#pragma unroll
    for (int mt = 0; mt < 4; ++mt) {
      int r = wm + mt * 16 + lr;
      short4v lo = *(const short4v*)(Asb + r * 256 + (kb ^ ((r & 7) << 4)));
      short4v hi = *(const short4v*)(Asb + r * 256 + ((kb + 32) ^ ((r & 7) << 4)));
      a[mt] = __builtin_shufflevector(lo, hi, 0, 1, 2, 3, 4, 5, 6, 7);
    }
#pragma unroll
    for (int nt = 0; nt < 4; ++nt) {
      int r = wn + nt * 16 + lr;
      short4v lo = *(const short4v*)(Bsb + r * 256 + (kb ^ ((r & 7) << 4)));
      short4v hi = *(const short4v*)(Bsb + r * 256 + ((kb + 32) ^ ((r & 7) << 4)));
      b[nt] = __builtin_shufflevector(lo, hi, 0, 1, 2, 3, 4, 5, 6, 7);
    }
#pragma unroll
    for (int mt = 0; mt < 4; ++mt)
#pragma unroll
      for (int nt = 0; nt < 4; ++nt)
        acc[mt][nt] = __builtin_amdgcn_mfma_f32_16x16x32_bf16(a[mt], b[nt], acc[mt][nt], 0, 0, 0);
  }

  float sc[4] = {0.f, 0.f, 0.f, 0.f}, scc[4] = {0.f, 0.f, 0.f, 0.f};
  bool bfdest = SPLIT && (bcol == 0);
#pragma unroll
  for (int mt = 0; mt < 4; ++mt) {
#pragma unroll
    for (int nt = 0; nt < 4; ++nt) {
      int col = bcol + wn + nt * 16 + lr;
      float bv = bias ? bias[col] : 0.f;
#pragma unroll
      for (int r4 = 0; r4 < 4; ++r4) {
        int row = brow + wm + mt * 16 + lg * 4 + r4;
        if (row < N) {
          float v = acc[mt][nt][r4] + bv;
          if (relu) v = fmaxf(v, 0.f);
          if (bfdest) {
            Csplit[(size_t)row * 128 + col] = f2b(v);
          } else {
            int cc = SPLIT ? (col - 128) : col;
            if (OBF) ((unsigned short*)Co)[(size_t)row * ldC + cc] = f2b(v);
            else ((float*)Co)[(size_t)row * ldC + cc] = v;
          }
          if (STATS) { sc[nt] += v; scc[nt] += v * v; }
        }
      }
    }
  }
  if (STATS) {
#pragma unroll
    for (int nt = 0; nt < 4; ++nt) {
      float s = sc[nt], ss = scc[nt];
      s += __shfl_xor(s, 16); s += __shfl_xor(s, 32);
      ss += __shfl_xor(ss, 16); ss += __shfl_xor(ss, 32);
      if (lg == 0) {
        int col = bcol + wn + nt * 16 + lr;
        atomicAdd(&psum[col], s);
        atomicAdd(&psqs[col], ss);
      }
    }
    if (FIN) {
      __shared__ int lastFlag;
      __syncthreads();
      __threadfence();
      if (tid == 0) {
        int old = atomicAdd(cnt, 1);
        lastFlag = (old == (int)(gridDim.x * gridDim.y) - 1) ? 1 : 0;
      }
      __syncthreads();
      if (lastFlag && tid < D) {
        float s = atomicAdd(&psum[tid], 0.f);
        float ss = atomicAdd(&psqs[tid], 0.f);
        float m = s * invN;
        float var = ss * invN - m * m;
        float a = gamma[tid] * rsqrtf(var + EPSBN);
        coefOut[tid] = a;
        coefOut[D + tid] = beta[tid] - m * a;
      }
    }
  }
}

// ---------------- GCN gather (CSR, bf16 rows in, f32 + bf16 out) ----------------
__global__ __launch_bounds__(256) void k_gcn_gather(const int* __restrict__ rowptr, const int* __restrict__ csr_src,
                                                    const float* __restrict__ dis,
                                                    const unsigned short* __restrict__ hp,
                                                    const float* __restrict__ bg,
                                                    float* __restrict__ c, unsigned short* __restrict__ cbf, int N) {
  int t = blockIdx.x * 256 + threadIdx.x;
  int g = t >> 5, lane = t & 31;
  if (g >= N) return;
  int off = lane << 2;
  float dd = dis[g];
  float w0 = dd * dd;
  float4 acc = *(const float4*)(bg + off);
  short4v hv = *(const short4v*)(hp + ((size_t)g << 7) + off);
  acc.x += w0 * b2f((unsigned short)hv[0]);
  acc.y += w0 * b2f((unsigned short)hv[1]);
  acc.z += w0 * b2f((unsigned short)hv[2]);
  acc.w += w0 * b2f((unsigned short)hv[3]);
  int beg = rowptr[g], end = rowptr[g + 1];
  int j = beg;
  for (; j + 3 < end; j += 4) {
    int s0 = csr_src[j], s1 = csr_src[j + 1], s2 = csr_src[j + 2], s3 = csr_src[j + 3];
    float n0 = dis[s0] * dd, n1 = dis[s1] * dd, n2 = dis[s2] * dd, n3 = dis[s3] * dd;
    short4v v0 = *(const short4v*)(hp + ((size_t)s0 << 7) + off);
    short4v v1 = *(const short4v*)(hp + ((size_t)s1 << 7) + off);
    short4v v2 = *(const short4v*)(hp + ((size_t)s2 << 7) + off);
    short4v v3 = *(const short4v*)(hp + ((size_t)s3 << 7) + off);
    acc.x += n0 * b2f((unsigned short)v0[0]) + n1 * b2f((unsigned short)v1[0]) + n2 * b2f((unsigned short)v2[0]) + n3 * b2f((unsigned short)v3[0]);
    acc.y += n0 * b2f((unsigned short)v0[1]) + n1 * b2f((unsigned short)v1[1]) + n2 * b2f((unsigned short)v2[1]) + n3 * b2f((unsigned short)v3[1]);
    acc.z += n0 * b2f((unsigned short)v0[2]) + n1 * b2f((unsigned short)v1[2]) + n2 * b2f((unsigned short)v2[2]) + n3 * b2f((unsigned short)v3[2]);
    acc.w += n0 * b2f((unsigned short)v0[3]) + n1 * b2f((unsigned short)v1[3]) + n2 * b2f((unsigned short)v2[3]) + n3 * b2f((unsigned short)v3[3]);
  }
  for (; j < end; ++j) {
    int s0 = csr_src[j];
    float n0 = dis[s0] * dd;
    short4v v0 = *(const short4v*)(hp + ((size_t)s0 << 7) + off);
    acc.x += n0 * b2f((unsigned short)v0[0]);
    acc.y += n0 * b2f((unsigned short)v0[1]);
    acc.z += n0 * b2f((unsigned short)v0[2]);
    acc.w += n0 * b2f((unsigned short)v0[3]);
  }
  *(float4*)(c + ((size_t)g << 7) + off) = acc;   // f32 for GRU's recurrent cv
  short4v b;
  b[0] = (short)f2b(acc.x); b[1] = (short)f2b(acc.y);
  b[2] = (short)f2b(acc.z); b[3] = (short)f2b(acc.w);
  *(short4v*)(cbf + ((size_t)g << 7) + off) = b;  // bf16 for GEMM2
}

// ---------------- GRU gates + stats + coef finalize ----------------
__global__ __launch_bounds__(512) void k_gru(const unsigned short* __restrict__ gib,
                                             const unsigned short* __restrict__ ghb,
                                             const float* __restrict__ cf,
                                             float* __restrict__ cb,
                                             float* __restrict__ psum, float* __restrict__ psqs,
                                             const float* __restrict__ gamma, const float* __restrict__ beta,
                                             float* __restrict__ coefOut, int* __restrict__ cnt,
                                             float invN, int N) {
  int tx = threadIdx.x & 127, ty = threadIdx.x >> 7;
  int n0 = blockIdx.x * 128;
  float s = 0.f, ss = 0.f;
  for (int r = ty; r < 128; r += 4) {
    int n = n0 + r;
    if (n >= N) break;
    size_t bi = (size_t)n * 384 + tx;
    float ir = b2f(gib[bi]), iz = b2f(gib[bi + 128]), in_ = b2f(gib[bi + 256]);
    float hr = b2f(ghb[bi]), hz = b2f(ghb[bi + 128]), hn_ = b2f(ghb[bi + 256]);
    float cv = cf[(size_t)n * 128 + tx];
    float rr = 1.f / (1.f + expf(-(ir + hr)));
    float z  = 1.f / (1.f + expf(-(iz + hz)));
    float nn = tanhf(in_ + rr * hn_);
    float v = (1.f - z) * nn + z * cv;
    cb[(size_t)n * 128 + tx] = v;
    s += v; ss += v * v;
  }
  __shared__ float sd[2][4][128];
  sd[0][ty][tx] = s; sd[1][ty][tx] = ss;
  __syncthreads();
  if (ty == 0) {
    s  = sd[0][0][tx] + sd[0][1][tx] + sd[0][2][tx] + sd[0][3][tx];
    ss = sd[1][0][tx] + sd[1][1][tx] + sd[1][2][tx] + sd[1][3][tx];
    atomicAdd(&psum[tx], s);
    atomicAdd(&psqs[tx], ss);
  }
  __shared__ int lastFlag;
  __syncthreads();
  __threadfence();
  if (threadIdx.x == 0) {
    int old = atomicAdd(cnt, 1);
    lastFlag = (old == (int)gridDim.x - 1) ? 1 : 0;
  }
  __syncthreads();
  if (lastFlag && threadIdx.x < 128) {
    int t = threadIdx.x;
    float sm = atomicAdd(&psum[t], 0.f);
    float sq = atomicAdd(&psqs[t], 0.f);
    float m = sm * invN;
    float var = sq * invN - m * m;
    float a = gamma[t] * rsqrtf(var + EPSBN);
    coefOut[t] = a;
    coefOut[128 + t] = beta[t] - m * a;
  }
}

// ---------------- final BN apply: mx=max(mx,bn(x)), stats(mx) + FIN coefO ----------------
__global__ __launch_bounds__(512) void k_bn_final(const float* __restrict__ x,
                                                  const float* __restrict__ psum, const float* __restrict__ psqs,
                                                  const float* __restrict__ gamma, const float* __restrict__ beta,
                                                  float invN,
                                                  unsigned short* __restrict__ mx,
                                                  float* __restrict__ npsum, float* __restrict__ npsqs,
                                                  const float* __restrict__ gammaO, const float* __restrict__ betaO,
                                                  float* __restrict__ coefOut, int* __restrict__ cnt,
                                                  int N) {
  __shared__ float cA[128], cB[128];
  int t = threadIdx.x;
  if (t < 128) {
    float m = psum[t] * invN;
    float var = psqs[t] * invN - m * m;
    float a = gamma[t] * rsqrtf(var + EPSBN);
    cA[t] = a; cB[t] = beta[t] - m * a;
  }
  __syncthreads();
  int tx = t & 127, ty = t >> 7;
  int n0 = blockIdx.x * 128;
  float s = 0.f, ss = 0.f;
  for (int r = ty; r < 128; r += 4) {
    int n = n0 + r;
    if (n >= N) break;
    size_t i = (size_t)n * 128 + tx;
    float v = x[i] * cA[tx] + cB[tx];
    float w = fmaxf(b2f(mx[i]), v);
    mx[i] = f2b(w);
    s += w; ss += w * w;
  }
  __shared__ float sd[2][4][128];
  sd[0][ty][tx] = s; sd[1][ty][tx] = ss;
  __syncthreads();
  if (ty == 0) {
    s  = sd[0][0][tx] + sd[0][1][tx] + sd[0][2][tx] + sd[0][3][tx];
    ss = sd[1][0][tx] + sd[1][1][tx] + sd[1][2][tx] + sd[1][3][tx];
    atomicAdd(&npsum[tx], s);
    atomicAdd(&npsqs[tx], ss);
  }
  __shared__ int lastFlag;
  __syncthreads();
  __threadfence();
  if (threadIdx.x == 0) {
    int old = atomicAdd(cnt, 1);
    lastFlag = (old == (int)gridDim.x - 1) ? 1 : 0;
  }
  __syncthreads();
  if (lastFlag && threadIdx.x < 128) {
    int c = threadIdx.x;
    float sm = atomicAdd(&npsum[c], 0.f);
    float sq = atomicAdd(&npsqs[c], 0.f);
    float m = sm * invN;
    float var = sq * invN - m * m;
    float a = gammaO[c] * rsqrtf(var + EPSBN);
    coefOut[c] = a;
    coefOut[128 + c] = betaO[c] - m * a;
  }
}

// ---------------- final matvec with fused BN+relu ----------------
__global__ __launch_bounds__(256) void k_matvec(const unsigned short* __restrict__ y, const float* __restrict__ coef,
                                                const float* __restrict__ W2, const float* __restrict__ b2,
                                                float* __restrict__ out, int N) {
  int t = blockIdx.x * 256 + threadIdx.x;
  int row = t >> 6, lane = t & 63;
  if (row >= N) return;
  const unsigned short* yr = y + (size_t)row * 384;
  float s = 0.f;
#pragma unroll
  for (int k = 0; k < 4; ++k) {
    int c = lane + 64 * k;
    float v = fmaxf(b2f(yr[c]) * coef[c] + coef[256 + c], 0.f);
    s += v * W2[c];
  }
#pragma unroll
  for (int off = 32; off > 0; off >>= 1) s += __shfl_down(s, off);
  if (lane == 0) out[row] = s + b2[0];
}

// ---------------- host orchestration ----------------
extern "C" void kernel_launch(void* const* d_in, const int* in_sizes, int n_in,
                              void* d_out, int out_size, void* d_ws, size_t ws_size,
                              hipStream_t stream) {
  const float* x    = (const float*)d_in[0];
  const int*   ei   = (const int*)d_in[1];
  const float* W_in = (const float*)d_in[2];
  const float* b_in = (const float*)d_in[3];
  const float* g0   = (const float*)d_in[4];
  const float* be0  = (const float*)d_in[5];
  const float* W_g  = (const float*)d_in[6];
  const float* b_g  = (const float*)d_in[7];
  const float* W_ih = (const float*)d_in[8];
  const float* W_hh = (const float*)d_in[9];
  const float* b_ih = (const float*)d_in[10];
  const float* b_hh = (const float*)d_in[11];
  const float* g_c  = (const float*)d_in[12];
  const float* be_c = (const float*)d_in[13];
  const float* g_o  = (const float*)d_in[14];
  const float* be_o = (const float*)d_in[15];
  const float* W1   = (const float*)d_in[16];
  const float* b1   = (const float*)d_in[17];
  const float* g1   = (const float*)d_in[18];
  const float* be1  = (const float*)d_in[19];
  const float* W2   = (const float*)d_in[20];
  const float* b2   = (const float*)d_in[21];

  const int N = in_sizes[0] / 128;   // 30000
  const int E = in_sizes[1] / 2;     // 480000
  const int ND = N * 128;
  const float invN = 1.0f / (float)N;

  float* p   = (float*)d_ws;
  float* cb  = p; p += ND;               // f32: input-GEMM out / GRU hidden out
  float* cf  = p; p += ND;               // f32: conv out (GRU recurrent input)
  float* dis = p; p += ((N + 255) & ~255);
  float* stats = p; p += 8 * 512 + 8;
  float* coefs = p; p += 2560;
  float* fbias = p; p += 512;
  int*   rowptr  = (int*)p; p += ((N + 1 + 255) & ~255);
  int*   cursor  = (int*)p; p += ((N + 255) & ~255);
  int*   bsum    = (int*)p; p += 256;
  int*   degi    = (int*)p; p += ((N + 255) & ~255);
  int*   csr_src = (int*)p; p += E;
  unsigned short* hp_bf   = (unsigned short*)p;      // [N][128] conv input rows
  unsigned short* cb_bf   = hp_bf + (size_t)ND;      // [N][128] conv output bf16
  unsigned short* mx_bf   = cb_bf + (size_t)ND;      // [N][128] running max
  unsigned short* gib_bf  = mx_bf + (size_t)ND;      // [N][384] gi
  unsigned short* ghb_bf  = gib_bf + (size_t)N * 384;// [N][384] gh / y1
  unsigned short* fusedBT = ghb_bf + (size_t)N * 384;// [512][128]
  unsigned short* BThh    = fusedBT + 512 * 128;     // [384][128]
  unsigned short* BTin    = BThh + 384 * 128;        // [128][128]
  unsigned short* BT1     = BTin + 128 * 128;        // [256][128]

  int* cnt = (int*)(stats + 8 * 512);
  float* ps0 = stats;
  float* psc[5];
  for (int i = 0; i < 5; ++i) psc[i] = stats + 512 * (1 + i);
  float* pso = stats + 512 * 6;
  float* ps1 = stats + 512 * 7;
  float* coef0 = coefs;
  float* coefc[5];
  for (int i = 0; i < 5; ++i) coefc[i] = coefs + 256 * (1 + i);
  float* coefO = coefs + 256 * 6;
  float* coef1 = coefs + 256 * 7;

  dim3 blk(256);
  int rb = (N + 127) / 128;
  int NBLK = (N + 255) / 256;
  int bnb = (N + 127) / 128;

  // ---- preprocessing ----
  k_wprep<<<(168456 + N + 255) / 256, blk, 0, stream>>>(W_g, W_ih, W_hh, W_in, W1, b_ih,
                                                        fusedBT, BThh, BTin, BT1, fbias, stats, degi, N);
  k_count_deg<<<(E + 255) / 256, blk, 0, stream>>>(ei + E, degi, E);
  k_scan_p1<<<NBLK, blk, 0, stream>>>(degi, rowptr, bsum, dis, N);
  k_scan_p2<<<1, blk, 0, stream>>>(bsum, NBLK);
  k_scan_p3<<<(N + 256) / 256, blk, 0, stream>>>(rowptr, cursor, bsum, N, E);
  k_csr_fill<<<(E + 255) / 256, blk, 0, stream>>>(ei, ei + E, cursor, csr_src, E);

  // ---- input layer: cb = relu(x@W_in+b_in) f32, stats ps0, FIN -> coef0 ----
  k_mmx<0, 1, 0, 0, 0, 0, 1><<<dim3(1, rb), blk, 0, stream>>>(
      x, BTin, b_in, cb, nullptr, nullptr, nullptr,
      ps0, ps0 + 256, g0, be0, coef0, &cnt[0], invN, 128, N, 128, 128, 1);

  for (int it = 0; it < 5; ++it) {
    // GEMM1: A = bn(cb) via coef (staged), mx update (bcol 0), out [hp_bf | gib_bf]
    const float* cA = (it == 0) ? coef0 : coefc[it - 1];
    if (it == 0)
      k_mmx<0, 0, 1, 1, 1, 1, 0><<<dim3(4, rb), blk, 0, stream>>>(
          cb, fusedBT, fbias, gib_bf, hp_bf, cA, mx_bf,
          nullptr, nullptr, nullptr, nullptr, nullptr, nullptr, invN, 128, N, 128, 384, 0);
    else
      k_mmx<0, 0, 1, 1, 1, 2, 0><<<dim3(4, rb), blk, 0, stream>>>(
          cb, fusedBT, fbias, gib_bf, hp_bf, cA, mx_bf,
          nullptr, nullptr, nullptr, nullptr, nullptr, nullptr, invN, 128, N, 128, 384, 0);
    // GCN aggregate -> cf (f32) + cb_bf (bf16)
    k_gcn_gather<<<(N * 32 + 255) / 256, blk, 0, stream>>>(rowptr, csr_src, dis, hp_bf, b_g, cf, cb_bf, N);
    // gh = cb_bf @ W_hh^T -> ghb_bf
    k_mmx<1, 0, 0, 1, 0, 0, 0><<<dim3(3, rb), blk, 0, stream>>>(
        cb_bf, BThh, b_hh, ghb_bf, nullptr, nullptr, nullptr,
        nullptr, nullptr, nullptr, nullptr, nullptr, nullptr, invN, 128, N, 128, 384, 0);
    // GRU -> cb f32, stats psc[it], FIN -> coefc[it]
    k_gru<<<bnb, 512, 0, stream>>>(gib_bf, ghb_bf, cf, cb,
                                   psc[it], psc[it] + 256, g_c, be_c,
                                   coefc[it], &cnt[1 + it], invN, N);
  }

  // ---- 5th h: mx=max(mx,bn(cb)), stats(mx)->pso, FIN -> coefO ----
  k_bn_final<<<bnb, 512, 0, stream>>>(cb, psc[4], psc[4] + 256, g_c, be_c, invN,
                                      mx_bf, pso, pso + 256, g_o, be_o, coefO, &cnt[6], N);
  // ---- encoder: A = bn(mx) via coefO, out ghb_bf, stats ps1, FIN -> coef1 ----
  k_mmx<1, 1, 0, 1, 1, 0, 1><<<dim3(2, rb), blk, 0, stream>>>(
      mx_bf, BT1, b1, ghb_bf, nullptr, coefO, nullptr,
      ps1, ps1 + 256, g1, be1, coef1, &cnt[7], invN, 256, N, 128, 384, 0);
  k_matvec<<<(N * 64 + 255) / 256, blk, 0, stream>>>(ghb_bf, coef1, W2, b2, (float*)d_out, N);
}

// Round 9
// 834.057 us; speedup vs baseline: 1.1539x; 1.1539x over previous
//
#include <hip/hip_runtime.h>
#include <cmath>

#define EPSBN 1e-5f

typedef __attribute__((ext_vector_type(8))) short short8v;
typedef __attribute__((ext_vector_type(4))) short short4v;
typedef __attribute__((ext_vector_type(4))) float f32x4;

__device__ inline unsigned short f2b(float x) {
  union { float f; unsigned int u; } v; v.f = x;
  unsigned int b = v.u;
  return (unsigned short)((b + 0x7FFFu + ((b >> 16) & 1u)) >> 16);
}
__device__ inline float b2f(unsigned short x) {
  union { unsigned int u; float f; } v; v.u = ((unsigned int)x) << 16;
  return v.f;
}

// ---------------- fused weight prep + zero-init ----------------
__global__ __launch_bounds__(256) void k_wprep(const float* __restrict__ W_g, const float* __restrict__ W_ih,
                                               const float* __restrict__ W_hh, const float* __restrict__ W_in,
                                               const float* __restrict__ W1, const float* __restrict__ b_ih,
                                               unsigned short* __restrict__ fusedBT, unsigned short* __restrict__ BThh,
                                               unsigned short* __restrict__ BTin, unsigned short* __restrict__ BT1,
                                               float* __restrict__ fbias, float* __restrict__ stats,
                                               int* __restrict__ degi, int N) {
  int i = blockIdx.x * 256 + threadIdx.x;
  if (i < 16384) {
    int k = i >> 7, m = i & 127;
    fusedBT[m * 128 + k] = f2b(W_g[i]);
  } else if (i < 65536) {
    int j = i - 16384;
    fusedBT[16384 + j] = f2b(W_ih[j]);
  } else if (i < 114688) {
    int j = i - 65536;
    BThh[j] = f2b(W_hh[j]);
  } else if (i < 131072) {
    int j = i - 114688;
    int k = j >> 7, m = j & 127;
    BTin[m * 128 + k] = f2b(W_in[j]);
  } else if (i < 163840) {
    int j = i - 131072;
    int k = j >> 8, m = j & 255;
    BT1[m * 128 + k] = f2b(W1[j]);
  } else if (i < 164352) {
    int j = i - 163840;
    fbias[j] = (j < 128) ? 0.f : b_ih[j - 128];
  } else if (i < 168448) {
    stats[i - 164352] = 0.f;
  } else if (i < 168448 + N) {
    degi[i - 168448] = 0;
  }
}

// ---------------- graph preprocessing ----------------
__global__ __launch_bounds__(256) void k_count_deg(const int* __restrict__ dst, int* __restrict__ deg, int E) {
  int i = blockIdx.x * 256 + threadIdx.x;
  if (i < E) atomicAdd(&deg[dst[i]], 1);
}

__global__ __launch_bounds__(256) void k_scan_p1(const int* __restrict__ deg, int* __restrict__ rowptr,
                                                 int* __restrict__ bsum, float* __restrict__ dis, int N) {
  __shared__ int sd[256];
  int t = threadIdx.x;
  int i = blockIdx.x * 256 + t;
  int v = (i < N) ? deg[i] : 0;
  if (i < N) dis[i] = rsqrtf((float)(v + 1));
  sd[t] = v;
  __syncthreads();
  for (int off = 1; off < 256; off <<= 1) {
    int u = (t >= off) ? sd[t - off] : 0;
    __syncthreads();
    sd[t] += u;
    __syncthreads();
  }
  if (i < N) rowptr[i] = sd[t] - v;
  if (t == 255) bsum[blockIdx.x] = sd[255];
}

__global__ void k_scan_p2(int* __restrict__ bsum, int NBLK) {
  __shared__ int sd[256];
  int t = threadIdx.x;
  int v = (t < NBLK) ? bsum[t] : 0;
  sd[t] = v;
  __syncthreads();
  for (int off = 1; off < 256; off <<= 1) {
    int u = (t >= off) ? sd[t - off] : 0;
    __syncthreads();
    sd[t] += u;
    __syncthreads();
  }
  if (t < NBLK) bsum[t] = sd[t] - v;
}

__global__ __launch_bounds__(256) void k_scan_p3(int* __restrict__ rowptr, int* __restrict__ cursor,
                                                 const int* __restrict__ bsum, int N, int E) {
  int i = blockIdx.x * 256 + threadIdx.x;
  if (i < N) {
    int v = rowptr[i] + bsum[blockIdx.x];
    rowptr[i] = v;
    cursor[i] = v;
  } else if (i == N) {
    rowptr[N] = E;
  }
}

__global__ __launch_bounds__(256) void k_csr_fill(const int* __restrict__ src, const int* __restrict__ dst,
                                                  int* __restrict__ cursor, int* __restrict__ csr_src, int E) {
  int e = blockIdx.x * 256 + threadIdx.x;
  if (e >= E) return;
  int s = src[e], d = dst[e];
  int pos = atomicAdd(&cursor[d], 1);
  csr_src[pos] = s;
}

// ---------------- bf16 MFMA matmul ----------------
// C = A[N,128] @ BT^T, BT is [M][128] bf16. 128x128 tile, K=128, 4 waves.
// A staged in LDS (XOR swizzle); B fragments read DIRECTLY from global
// (BT col-block is 32KB, L1/L2-hot) -> LDS 32.8KB -> 4 blocks/CU.
// SPLIT: col-block 0 -> Csplit bf16 ld128; cols>=128 -> Co at col-128.
// OBF: Co is bf16. BNA: y=cA[k]*a+cB[k] during A staging (bf16 A only).
template<int ABF, int STATS, int SPLIT, int OBF, int BNA>
__global__ __launch_bounds__(256) void k_mmx(const void* __restrict__ Ap, const unsigned short* __restrict__ BT,
                                             const float* __restrict__ bias,
                                             void* __restrict__ Co, unsigned short* __restrict__ Csplit,
                                             const float* __restrict__ coefA,
                                             float* __restrict__ psum, float* __restrict__ psqs,
                                             int N, int ldA, int ldC, int relu)
{
  __shared__ unsigned short As[128 * 128];
  char* Asb = (char*)As;
  int tid = threadIdx.x;
  int brow = blockIdx.y * 128, bcol = blockIdx.x * 128;

#pragma unroll
  for (int p = 0; p < 8; ++p) {
    int idx = p * 256 + tid;
    int r = idx >> 4, ch = idx & 15;
    int arow = brow + r;
    short8v v = {0, 0, 0, 0, 0, 0, 0, 0};
    if (ABF) {
      if (arow < N) v = *(const short8v*)((const unsigned short*)Ap + (size_t)arow * ldA + ch * 8);
      if (BNA) {
#pragma unroll
        for (int j = 0; j < 8; ++j) {
          int k = ch * 8 + j;
          float f = b2f((unsigned short)v[j]) * coefA[k] + coefA[128 + k];
          v[j] = (short)f2b(f);
        }
      }
    } else {
      if (arow < N) {
        const float* a = (const float*)Ap + (size_t)arow * ldA + ch * 8;
        f32x4 x0 = *(const f32x4*)a;
        f32x4 x1 = *(const f32x4*)(a + 4);
        v[0] = (short)f2b(x0[0]); v[1] = (short)f2b(x0[1]);
        v[2] = (short)f2b(x0[2]); v[3] = (short)f2b(x0[3]);
        v[4] = (short)f2b(x1[0]); v[5] = (short)f2b(x1[1]);
        v[6] = (short)f2b(x1[2]); v[7] = (short)f2b(x1[3]);
      }
    }
    *(short8v*)(Asb + r * 256 + ((ch * 16) ^ ((r & 7) << 4))) = v;
  }
  __syncthreads();

  int w = tid >> 6, l = tid & 63;
  int wm = (w >> 1) * 64, wn = (w & 1) * 64;
  int lg = l >> 4, lr = l & 15;
  f32x4 acc[4][4] = {};

#pragma unroll
  for (int ks = 0; ks < 4; ++ks) {
    int kb = ks * 64 + lg * 8;
    short8v a[4], b[4];
#pragma unroll
    for (int mt = 0; mt < 4; ++mt) {
      int r = wm + mt * 16 + lr;
      short4v lo = *(const short4v*)(Asb + r * 256 + (kb ^ ((r & 7) << 4)));
      short4v hi = *(const short4v*)(Asb + r * 256 + ((kb + 32) ^ ((r & 7) << 4)));
      a[mt] = __builtin_shufflevector(lo, hi, 0, 1, 2, 3, 4, 5, 6, 7);
    }
#pragma unroll
    for (int nt = 0; nt < 4; ++nt) {
      const unsigned short* bp = BT + (size_t)(bcol + wn + nt * 16 + lr) * 128 + ks * 32 + lg * 4;
      short4v lo = *(const short4v*)bp;
      short4v hi = *(const short4v*)(bp + 16);
      b[nt] = __builtin_shufflevector(lo, hi, 0, 1, 2, 3, 4, 5, 6, 7);
    }
#pragma unroll
    for (int mt = 0; mt < 4; ++mt)
#pragma unroll
      for (int nt = 0; nt < 4; ++nt)
        acc[mt][nt] = __builtin_amdgcn_mfma_f32_16x16x32_bf16(a[mt], b[nt], acc[mt][nt], 0, 0, 0);
  }

  float sc[4] = {0.f, 0.f, 0.f, 0.f}, scc[4] = {0.f, 0.f, 0.f, 0.f};
  bool bfdest = SPLIT && (bcol == 0);
#pragma unroll
  for (int mt = 0; mt < 4; ++mt) {
#pragma unroll
    for (int nt = 0; nt < 4; ++nt) {
      int col = bcol + wn + nt * 16 + lr;
      float bv = bias ? bias[col] : 0.f;
#pragma unroll
      for (int r4 = 0; r4 < 4; ++r4) {
        int row = brow + wm + mt * 16 + lg * 4 + r4;
        if (row < N) {
          float v = acc[mt][nt][r4] + bv;
          if (relu) v = fmaxf(v, 0.f);
          if (bfdest) {
            Csplit[(size_t)row * 128 + col] = f2b(v);
          } else {
            int cc = SPLIT ? (col - 128) : col;
            if (OBF) ((unsigned short*)Co)[(size_t)row * ldC + cc] = f2b(v);
            else ((float*)Co)[(size_t)row * ldC + cc] = v;
          }
          if (STATS) { sc[nt] += v; scc[nt] += v * v; }
        }
      }
    }
  }
  if (STATS) {
#pragma unroll
    for (int nt = 0; nt < 4; ++nt) {
      float s = sc[nt], ss = scc[nt];
      s += __shfl_xor(s, 16); s += __shfl_xor(s, 32);
      ss += __shfl_xor(ss, 16); ss += __shfl_xor(ss, 32);
      if (lg == 0) {
        int col = bcol + wn + nt * 16 + lr;
        atomicAdd(&psum[col], s);
        atomicAdd(&psqs[col], ss);
      }
    }
  }
}

// ---------------- GCN gather (CSR, bf16 rows in, f32 + bf16 out) ----------------
__global__ __launch_bounds__(256) void k_gcn_gather(const int* __restrict__ rowptr, const int* __restrict__ csr_src,
                                                    const float* __restrict__ dis,
                                                    const unsigned short* __restrict__ hp,
                                                    const float* __restrict__ bg,
                                                    float* __restrict__ c, unsigned short* __restrict__ cbf, int N) {
  int t = blockIdx.x * 256 + threadIdx.x;
  int g = t >> 5, lane = t & 31;
  if (g >= N) return;
  int off = lane << 2;
  float dd = dis[g];
  float w0 = dd * dd;
  float4 acc = *(const float4*)(bg + off);
  short4v hv = *(const short4v*)(hp + ((size_t)g << 7) + off);
  acc.x += w0 * b2f((unsigned short)hv[0]);
  acc.y += w0 * b2f((unsigned short)hv[1]);
  acc.z += w0 * b2f((unsigned short)hv[2]);
  acc.w += w0 * b2f((unsigned short)hv[3]);
  int beg = rowptr[g], end = rowptr[g + 1];
  int j = beg;
  for (; j + 3 < end; j += 4) {
    int s0 = csr_src[j], s1 = csr_src[j + 1], s2 = csr_src[j + 2], s3 = csr_src[j + 3];
    float n0 = dis[s0] * dd, n1 = dis[s1] * dd, n2 = dis[s2] * dd, n3 = dis[s3] * dd;
    short4v v0 = *(const short4v*)(hp + ((size_t)s0 << 7) + off);
    short4v v1 = *(const short4v*)(hp + ((size_t)s1 << 7) + off);
    short4v v2 = *(const short4v*)(hp + ((size_t)s2 << 7) + off);
    short4v v3 = *(const short4v*)(hp + ((size_t)s3 << 7) + off);
    acc.x += n0 * b2f((unsigned short)v0[0]) + n1 * b2f((unsigned short)v1[0]) + n2 * b2f((unsigned short)v2[0]) + n3 * b2f((unsigned short)v3[0]);
    acc.y += n0 * b2f((unsigned short)v0[1]) + n1 * b2f((unsigned short)v1[1]) + n2 * b2f((unsigned short)v2[1]) + n3 * b2f((unsigned short)v3[1]);
    acc.z += n0 * b2f((unsigned short)v0[2]) + n1 * b2f((unsigned short)v1[2]) + n2 * b2f((unsigned short)v2[2]) + n3 * b2f((unsigned short)v3[2]);
    acc.w += n0 * b2f((unsigned short)v0[3]) + n1 * b2f((unsigned short)v1[3]) + n2 * b2f((unsigned short)v2[3]) + n3 * b2f((unsigned short)v3[3]);
  }
  for (; j < end; ++j) {
    int s0 = csr_src[j];
    float n0 = dis[s0] * dd;
    short4v v0 = *(const short4v*)(hp + ((size_t)s0 << 7) + off);
    acc.x += n0 * b2f((unsigned short)v0[0]);
    acc.y += n0 * b2f((unsigned short)v0[1]);
    acc.z += n0 * b2f((unsigned short)v0[2]);
    acc.w += n0 * b2f((unsigned short)v0[3]);
  }
  *(float4*)(c + ((size_t)g << 7) + off) = acc;
  short4v b;
  b[0] = (short)f2b(acc.x); b[1] = (short)f2b(acc.y);
  b[2] = (short)f2b(acc.z); b[3] = (short)f2b(acc.w);
  *(short4v*)(cbf + ((size_t)g << 7) + off) = b;
}

// ---------------- GRU gates (bf16 gate inputs, f32 recurrent, fused BN stats) ----------------
__global__ __launch_bounds__(512) void k_gru(const unsigned short* __restrict__ gib,
                                             const unsigned short* __restrict__ ghb,
                                             float* __restrict__ cb,
                                             float* __restrict__ psum, float* __restrict__ psqs, int N) {
  int tx = threadIdx.x & 127, ty = threadIdx.x >> 7;
  int n0 = blockIdx.x * 128;
  float s = 0.f, ss = 0.f;
  for (int r = ty; r < 128; r += 4) {
    int n = n0 + r;
    if (n >= N) break;
    size_t bi = (size_t)n * 384 + tx;
    float ir = b2f(gib[bi]), iz = b2f(gib[bi + 128]), in_ = b2f(gib[bi + 256]);
    float hr = b2f(ghb[bi]), hz = b2f(ghb[bi + 128]), hn_ = b2f(ghb[bi + 256]);
    float cv = cb[(size_t)n * 128 + tx];
    float rr = 1.f / (1.f + expf(-(ir + hr)));
    float z  = 1.f / (1.f + expf(-(iz + hz)));
    float nn = tanhf(in_ + rr * hn_);
    float v = (1.f - z) * nn + z * cv;
    cb[(size_t)n * 128 + tx] = v;
    s += v; ss += v * v;
  }
  __shared__ float sd[2][4][128];
  sd[0][ty][tx] = s; sd[1][ty][tx] = ss;
  __syncthreads();
  if (ty == 0) {
    s  = sd[0][0][tx] + sd[0][1][tx] + sd[0][2][tx] + sd[0][3][tx];
    ss = sd[1][0][tx] + sd[1][1][tx] + sd[1][2][tx] + sd[1][3][tx];
    atomicAdd(&psum[tx], s);
    atomicAdd(&psqs[tx], ss);
  }
}

// ---------------- BN apply (bf16 outputs + bf16 running max) ----------------
// MODE: 1 w=max(mx,v)->mx; 3 mx=v. STATS: stats of w -> npsum/npsqs.
template<int MODE, int STATS>
__global__ __launch_bounds__(512) void k_bn_apply(const float* __restrict__ x, int ldx,
                                                  const float* __restrict__ psum, const float* __restrict__ psqs,
                                                  const float* __restrict__ gamma, const float* __restrict__ beta,
                                                  float invN,
                                                  unsigned short* __restrict__ yb, unsigned short* __restrict__ mx,
                                                  float* __restrict__ npsum, float* __restrict__ npsqs,
                                                  int N, int R) {
  __shared__ float cA[128], cB[128];
  int t = threadIdx.x;
  if (t < 128) {
    float m = psum[t] * invN;
    float var = psqs[t] * invN - m * m;
    float a = gamma[t] * rsqrtf(var + EPSBN);
    cA[t] = a; cB[t] = beta[t] - m * a;
  }
  __syncthreads();
  int tx = t & 127, ty = t >> 7;
  int n0 = blockIdx.x * R;
  float s = 0.f, ss = 0.f;
  for (int r = ty; r < R; r += 4) {
    int n = n0 + r;
    if (n >= N) break;
    size_t i = (size_t)n * 128 + tx;
    float v = x[(size_t)n * ldx + tx] * cA[tx] + cB[tx];
    float w = v;
    if (MODE == 1) {
      w = fmaxf(b2f(mx[i]), v);
      mx[i] = f2b(w);
    } else {
      mx[i] = f2b(v);
    }
    yb[i] = f2b(v);
    if (STATS) { s += w; ss += w * w; }
  }
  if (STATS) {
    __shared__ float sd[2][4][128];
    sd[0][ty][tx] = s; sd[1][ty][tx] = ss;
    __syncthreads();
    if (ty == 0) {
      for (int q = 1; q < 4; ++q) { s += sd[0][q][tx]; ss += sd[1][q][tx]; }
      atomicAdd(&npsum[tx], s);
      atomicAdd(&npsqs[tx], ss);
    }
  }
}

// ---------------- BN coef ----------------
__global__ void k_coef(const float* __restrict__ psum, const float* __restrict__ psqs,
                       const float* __restrict__ gamma, const float* __restrict__ beta,
                       float invN, float* __restrict__ coef, int D) {
  int t = threadIdx.x;
  if (t < D) {
    float m = psum[t] * invN;
    float var = psqs[t] * invN - m * m;
    float a = gamma[t] * rsqrtf(var + EPSBN);
    coef[t] = a;
    coef[D + t] = beta[t] - m * a;
  }
}

// ---------------- final matvec with fused BN+relu ----------------
__global__ __launch_bounds__(256) void k_matvec(const unsigned short* __restrict__ y, const float* __restrict__ coef,
                                                const float* __restrict__ W2, const float* __restrict__ b2,
                                                float* __restrict__ out, int N) {
  int t = blockIdx.x * 256 + threadIdx.x;
  int row = t >> 6, lane = t & 63;
  if (row >= N) return;
  const unsigned short* yr = y + (size_t)row * 384;
  float s = 0.f;
#pragma unroll
  for (int k = 0; k < 4; ++k) {
    int c = lane + 64 * k;
    float v = fmaxf(b2f(yr[c]) * coef[c] + coef[256 + c], 0.f);
    s += v * W2[c];
  }
#pragma unroll
  for (int off = 32; off > 0; off >>= 1) s += __shfl_down(s, off);
  if (lane == 0) out[row] = s + b2[0];
}

// ---------------- host orchestration ----------------
extern "C" void kernel_launch(void* const* d_in, const int* in_sizes, int n_in,
                              void* d_out, int out_size, void* d_ws, size_t ws_size,
                              hipStream_t stream) {
  const float* x    = (const float*)d_in[0];
  const int*   ei   = (const int*)d_in[1];
  const float* W_in = (const float*)d_in[2];
  const float* b_in = (const float*)d_in[3];
  const float* g0   = (const float*)d_in[4];
  const float* be0  = (const float*)d_in[5];
  const float* W_g  = (const float*)d_in[6];
  const float* b_g  = (const float*)d_in[7];
  const float* W_ih = (const float*)d_in[8];
  const float* W_hh = (const float*)d_in[9];
  const float* b_ih = (const float*)d_in[10];
  const float* b_hh = (const float*)d_in[11];
  const float* g_c  = (const float*)d_in[12];
  const float* be_c = (const float*)d_in[13];
  const float* g_o  = (const float*)d_in[14];
  const float* be_o = (const float*)d_in[15];
  const float* W1   = (const float*)d_in[16];
  const float* b1   = (const float*)d_in[17];
  const float* g1   = (const float*)d_in[18];
  const float* be1  = (const float*)d_in[19];
  const float* W2   = (const float*)d_in[20];
  const float* b2   = (const float*)d_in[21];

  const int N = in_sizes[0] / 128;   // 30000
  const int E = in_sizes[1] / 2;     // 480000
  const int ND = N * 128;
  const float invN = 1.0f / (float)N;

  float* p   = (float*)d_ws;
  float* cb  = p; p += ND;               // f32: input-GEMM staging / conv out / GRU hidden
  float* dis = p; p += ((N + 255) & ~255);
  float* stats = p; p += 8 * 512;
  float* fbias = p; p += 512;
  float* coefO = p; p += 256;
  float* coef1 = p; p += 512;
  int*   degi    = (int*)p; p += ((N + 255) & ~255);
  int*   rowptr  = (int*)p; p += ((N + 1 + 255) & ~255);
  int*   cursor  = (int*)p; p += ((N + 255) & ~255);
  int*   bsum    = (int*)p; p += 256;
  int*   csr_src = (int*)p; p += E;
  unsigned short* h_bf    = (unsigned short*)p;      // [N][128] post-BN hidden
  unsigned short* hp_bf   = h_bf + (size_t)ND;       // [N][128] conv input rows
  unsigned short* cb_bf   = hp_bf + (size_t)ND;      // [N][128] conv output
  unsigned short* mx_bf   = cb_bf + (size_t)ND;      // [N][128] running max
  unsigned short* gib_bf  = mx_bf + (size_t)ND;      // [N][384] gi
  unsigned short* ghb_bf  = gib_bf + (size_t)N * 384;// [N][384] gh / y1
  unsigned short* fusedBT = ghb_bf + (size_t)N * 384;// [512][128]
  unsigned short* BThh    = fusedBT + 512 * 128;     // [384][128]
  unsigned short* BTin    = BThh + 384 * 128;        // [128][128]
  unsigned short* BT1     = BTin + 128 * 128;        // [256][128]

  float* ps0 = stats;
  float* psc[5];
  for (int i = 0; i < 5; ++i) psc[i] = stats + 512 * (1 + i);
  float* pso = stats + 512 * 6;
  float* ps1 = stats + 512 * 7;

  dim3 blk(256);
  int rb = (N + 127) / 128;
  int NBLK = (N + 255) / 256;
  int bnb = (N + 127) / 128;

  // ---- preprocessing ----
  k_wprep<<<(168448 + N + 255) / 256, blk, 0, stream>>>(W_g, W_ih, W_hh, W_in, W1, b_ih,
                                                        fusedBT, BThh, BTin, BT1, fbias, stats, degi, N);
  k_count_deg<<<(E + 255) / 256, blk, 0, stream>>>(ei + E, degi, E);
  k_scan_p1<<<NBLK, blk, 0, stream>>>(degi, rowptr, bsum, dis, N);
  k_scan_p2<<<1, blk, 0, stream>>>(bsum, NBLK);
  k_scan_p3<<<(N + 256) / 256, blk, 0, stream>>>(rowptr, cursor, bsum, N, E);
  k_csr_fill<<<(E + 255) / 256, blk, 0, stream>>>(ei, ei + E, cursor, csr_src, E);

  // ---- input layer: relu(x@W_in+b_in) -> cb (f32 ld128), stats ps0 ----
  k_mmx<0, 1, 0, 0, 0><<<dim3(1, rb), blk, 0, stream>>>(x, BTin, b_in, cb, nullptr, nullptr,
                                                        ps0, ps0 + 256, N, 128, 128, 1);
  k_bn_apply<3, 0><<<bnb, 512, 0, stream>>>(cb, 128, ps0, ps0 + 256, g0, be0, invN,
                                            h_bf, mx_bf, nullptr, nullptr, N, 128);

  for (int it = 0; it < 5; ++it) {
    // fused GEMM: col0 -> hp_bf (bf16), cols 128..511 -> gib_bf (bf16 ld384)
    k_mmx<1, 0, 1, 1, 0><<<dim3(4, rb), blk, 0, stream>>>(h_bf, fusedBT, fbias, gib_bf, hp_bf, nullptr,
                                                          nullptr, nullptr, N, 128, 384, 0);
    // GCN aggregate -> cb (f32 for GRU) + cb_bf (bf16 for GEMM2)
    k_gcn_gather<<<(N * 32 + 255) / 256, blk, 0, stream>>>(rowptr, csr_src, dis, hp_bf, b_g, cb, cb_bf, N);
    // gh = cb_bf @ W_hh^T -> ghb_bf (bf16 ld384)
    k_mmx<1, 0, 0, 1, 0><<<dim3(3, rb), blk, 0, stream>>>(cb_bf, BThh, b_hh, ghb_bf, nullptr, nullptr,
                                                          nullptr, nullptr, N, 128, 384, 0);
    // GRU gates: cb <- new hidden (in place), stats psc[it]
    k_gru<<<bnb, 512, 0, stream>>>(gib_bf, ghb_bf, cb, psc[it], psc[it] + 256, N);
    // BN + running max
    if (it < 4)
      k_bn_apply<1, 0><<<bnb, 512, 0, stream>>>(cb, 128, psc[it], psc[it] + 256, g_c, be_c, invN,
                                                h_bf, mx_bf, nullptr, nullptr, N, 128);
    else
      k_bn_apply<1, 1><<<bnb, 512, 0, stream>>>(cb, 128, psc[it], psc[it] + 256, g_c, be_c, invN,
                                                h_bf, mx_bf, pso, pso + 256, N, 128);
  }

  // ---- tail: coefO -> encoder GEMM (BN fused in staging) -> coef1 -> matvec ----
  k_coef<<<1, 128, 0, stream>>>(pso, pso + 256, g_o, be_o, invN, coefO, 128);
  k_mmx<1, 1, 0, 1, 1><<<dim3(2, rb), blk, 0, stream>>>(mx_bf, BT1, b1, ghb_bf, nullptr, coefO,
                                                        ps1, ps1 + 256, N, 128, 384, 0);
  k_coef<<<1, 256, 0, stream>>>(ps1, ps1 + 256, g1, be1, invN, coef1, 256);
  k_matvec<<<(N * 64 + 255) / 256, blk, 0, stream>>>(ghb_bf, coef1, W2, b2, (float*)d_out, N);
}

// Round 10
// 656.587 us; speedup vs baseline: 1.4658x; 1.2703x over previous
//
#include <hip/hip_runtime.h>
#include <cmath>

#define EPSBN 1e-5f

typedef __attribute__((ext_vector_type(8))) short short8v;
typedef __attribute__((ext_vector_type(4))) short short4v;
typedef __attribute__((ext_vector_type(4))) float f32x4;

__device__ inline unsigned short f2b(float x) {
  union { float f; unsigned int u; } v; v.f = x;
  unsigned int b = v.u;
  return (unsigned short)((b + 0x7FFFu + ((b >> 16) & 1u)) >> 16);
}
__device__ inline float b2f(unsigned short x) {
  union { unsigned int u; float f; } v; v.u = ((unsigned int)x) << 16;
  return v.f;
}

// ---------------- fused weight prep + zero-init ----------------
__global__ __launch_bounds__(256) void k_wprep(const float* __restrict__ W_g, const float* __restrict__ W_ih,
                                               const float* __restrict__ W_hh, const float* __restrict__ W_in,
                                               const float* __restrict__ W1, const float* __restrict__ b_ih,
                                               unsigned short* __restrict__ fusedBT, unsigned short* __restrict__ BThh,
                                               unsigned short* __restrict__ BTin, unsigned short* __restrict__ BT1,
                                               float* __restrict__ fbias, float* __restrict__ stats,
                                               int* __restrict__ degi, int N) {
  int i = blockIdx.x * 256 + threadIdx.x;
  if (i < 16384) {
    int k = i >> 7, m = i & 127;
    fusedBT[m * 128 + k] = f2b(W_g[i]);
  } else if (i < 65536) {
    int j = i - 16384;
    fusedBT[16384 + j] = f2b(W_ih[j]);
  } else if (i < 114688) {
    int j = i - 65536;
    BThh[j] = f2b(W_hh[j]);
  } else if (i < 131072) {
    int j = i - 114688;
    int k = j >> 7, m = j & 127;
    BTin[m * 128 + k] = f2b(W_in[j]);
  } else if (i < 163840) {
    int j = i - 131072;
    int k = j >> 8, m = j & 255;
    BT1[m * 128 + k] = f2b(W1[j]);
  } else if (i < 164352) {
    int j = i - 163840;
    fbias[j] = (j < 128) ? 0.f : b_ih[j - 128];
  } else if (i < 168448) {
    stats[i - 164352] = 0.f;
  } else if (i < 168448 + N) {
    degi[i - 168448] = 0;
  }
}

// ---------------- graph preprocessing ----------------
__global__ __launch_bounds__(256) void k_count_deg(const int* __restrict__ dst, int* __restrict__ deg, int E) {
  int i = blockIdx.x * 256 + threadIdx.x;
  if (i < E) atomicAdd(&deg[dst[i]], 1);
}

__global__ __launch_bounds__(256) void k_scan_p1(const int* __restrict__ deg, int* __restrict__ rowptr,
                                                 int* __restrict__ bsum, float* __restrict__ dis, int N) {
  __shared__ int sd[256];
  int t = threadIdx.x;
  int i = blockIdx.x * 256 + t;
  int v = (i < N) ? deg[i] : 0;
  if (i < N) dis[i] = rsqrtf((float)(v + 1));
  sd[t] = v;
  __syncthreads();
  for (int off = 1; off < 256; off <<= 1) {
    int u = (t >= off) ? sd[t - off] : 0;
    __syncthreads();
    sd[t] += u;
    __syncthreads();
  }
  if (i < N) rowptr[i] = sd[t] - v;
  if (t == 255) bsum[blockIdx.x] = sd[255];
}

__global__ void k_scan_p2(int* __restrict__ bsum, int NBLK) {
  __shared__ int sd[256];
  int t = threadIdx.x;
  int v = (t < NBLK) ? bsum[t] : 0;
  sd[t] = v;
  __syncthreads();
  for (int off = 1; off < 256; off <<= 1) {
    int u = (t >= off) ? sd[t - off] : 0;
    __syncthreads();
    sd[t] += u;
    __syncthreads();
  }
  if (t < NBLK) bsum[t] = sd[t] - v;
}

__global__ __launch_bounds__(256) void k_scan_p3(int* __restrict__ rowptr, int* __restrict__ cursor,
                                                 const int* __restrict__ bsum, int N, int E) {
  int i = blockIdx.x * 256 + threadIdx.x;
  if (i < N) {
    int v = rowptr[i] + bsum[blockIdx.x];
    rowptr[i] = v;
    cursor[i] = v;
  } else if (i == N) {
    rowptr[N] = E;
  }
}

__global__ __launch_bounds__(256) void k_csr_fill(const int* __restrict__ src, const int* __restrict__ dst,
                                                  int* __restrict__ cursor, int* __restrict__ csr_src, int E) {
  int e = blockIdx.x * 256 + threadIdx.x;
  if (e >= E) return;
  int s = src[e], d = dst[e];
  int pos = atomicAdd(&cursor[d], 1);
  csr_src[pos] = s;
}

// ---------------- bf16 MFMA matmul ----------------
// C = A[N,128] @ BT^T, BT is [M][128] bf16. 128x128 tile, K=128, 4 waves.
// A and B staged in LDS (XOR swizzle). bf16 outputs go through an
// LDS-transposed epilogue: acc -> As image -> coalesced 16B row stores
// (kills partial-64B-sector write RMW seen as FETCH ~= A + writes/4).
// SPLIT: col-block 0 -> Csplit bf16 ld128; cols>=128 -> Co at col-128.
// OBF: Co is bf16. BNA: y=cA[k]*a+cB[k] during A staging (bf16 A only).
template<int ABF, int STATS, int SPLIT, int OBF, int BNA>
__global__ __launch_bounds__(256) void k_mmx(const void* __restrict__ Ap, const unsigned short* __restrict__ BT,
                                             const float* __restrict__ bias,
                                             void* __restrict__ Co, unsigned short* __restrict__ Csplit,
                                             const float* __restrict__ coefA,
                                             float* __restrict__ psum, float* __restrict__ psqs,
                                             int N, int ldA, int ldC, int relu)
{
  __shared__ unsigned short As[128 * 128];
  __shared__ unsigned short Bs[128 * 128];
  char* Asb = (char*)As;
  char* Bsb = (char*)Bs;
  int tid = threadIdx.x;
  int brow = blockIdx.y * 128, bcol = blockIdx.x * 128;

#pragma unroll
  for (int p = 0; p < 8; ++p) {
    int idx = p * 256 + tid;
    int r = idx >> 4, ch = idx & 15;
    int arow = brow + r;
    short8v v = {0, 0, 0, 0, 0, 0, 0, 0};
    if (ABF) {
      if (arow < N) v = *(const short8v*)((const unsigned short*)Ap + (size_t)arow * ldA + ch * 8);
      if (BNA) {
#pragma unroll
        for (int j = 0; j < 8; ++j) {
          int k = ch * 8 + j;
          float f = b2f((unsigned short)v[j]) * coefA[k] + coefA[128 + k];
          v[j] = (short)f2b(f);
        }
      }
    } else {
      if (arow < N) {
        const float* a = (const float*)Ap + (size_t)arow * ldA + ch * 8;
        f32x4 x0 = *(const f32x4*)a;
        f32x4 x1 = *(const f32x4*)(a + 4);
        v[0] = (short)f2b(x0[0]); v[1] = (short)f2b(x0[1]);
        v[2] = (short)f2b(x0[2]); v[3] = (short)f2b(x0[3]);
        v[4] = (short)f2b(x1[0]); v[5] = (short)f2b(x1[1]);
        v[6] = (short)f2b(x1[2]); v[7] = (short)f2b(x1[3]);
      }
    }
    *(short8v*)(Asb + r * 256 + ((ch * 16) ^ ((r & 7) << 4))) = v;
  }
#pragma unroll
  for (int p = 0; p < 8; ++p) {
    int idx = p * 256 + tid;
    int r = idx >> 4, ch = idx & 15;
    short8v v = *(const short8v*)(BT + (size_t)(bcol + r) * 128 + ch * 8);
    *(short8v*)(Bsb + r * 256 + ((ch * 16) ^ ((r & 7) << 4))) = v;
  }
  __syncthreads();

  int w = tid >> 6, l = tid & 63;
  int wm = (w >> 1) * 64, wn = (w & 1) * 64;
  int lg = l >> 4, lr = l & 15;
  f32x4 acc[4][4] = {};

#pragma unroll
  for (int ks = 0; ks < 4; ++ks) {
    int kb = ks * 64 + lg * 8;
    short8v a[4], b[4];
#pragma unroll
    for (int mt = 0; mt < 4; ++mt) {
      int r = wm + mt * 16 + lr;
      short4v lo = *(const short4v*)(Asb + r * 256 + (kb ^ ((r & 7) << 4)));
      short4v hi = *(const short4v*)(Asb + r * 256 + ((kb + 32) ^ ((r & 7) << 4)));
      a[mt] = __builtin_shufflevector(lo, hi, 0, 1, 2, 3, 4, 5, 6, 7);
    }
#pragma unroll
    for (int nt = 0; nt < 4; ++nt) {
      int r = wn + nt * 16 + lr;
      short4v lo = *(const short4v*)(Bsb + r * 256 + (kb ^ ((r & 7) << 4)));
      short4v hi = *(const short4v*)(Bsb + r * 256 + ((kb + 32) ^ ((r & 7) << 4)));
      b[nt] = __builtin_shufflevector(lo, hi, 0, 1, 2, 3, 4, 5, 6, 7);
    }
#pragma unroll
    for (int mt = 0; mt < 4; ++mt)
#pragma unroll
      for (int nt = 0; nt < 4; ++nt)
        acc[mt][nt] = __builtin_amdgcn_mfma_f32_16x16x32_bf16(a[mt], b[nt], acc[mt][nt], 0, 0, 0);
  }

  float sc[4] = {0.f, 0.f, 0.f, 0.f}, scc[4] = {0.f, 0.f, 0.f, 0.f};
  if (OBF) {
    // ---- LDS-transposed coalesced epilogue (bf16 outputs) ----
    __syncthreads();   // all MFMA reads of As done before overwrite
#pragma unroll
    for (int mt = 0; mt < 4; ++mt) {
#pragma unroll
      for (int nt = 0; nt < 4; ++nt) {
        int colL = wn + nt * 16 + lr;
        float bv = bias ? bias[bcol + colL] : 0.f;
#pragma unroll
        for (int r4 = 0; r4 < 4; ++r4) {
          int rowL = wm + mt * 16 + lg * 4 + r4;
          float v = acc[mt][nt][r4] + bv;
          if (relu) v = fmaxf(v, 0.f);
          *(unsigned short*)(Asb + rowL * 256 + ((colL * 2) ^ ((rowL & 7) << 4))) = f2b(v);
          if (STATS) {
            if (brow + rowL < N) { sc[nt] += v; scc[nt] += v * v; }
          }
        }
      }
    }
    __syncthreads();
    bool bfdest = SPLIT && (bcol == 0);
    int cbase = SPLIT ? (bcol - 128) : bcol;
#pragma unroll
    for (int p = 0; p < 8; ++p) {
      int idx = p * 256 + tid;
      int r = idx >> 4, ch = idx & 15;
      int arow = brow + r;
      if (arow < N) {
        short8v v = *(const short8v*)(Asb + r * 256 + ((ch * 16) ^ ((r & 7) << 4)));
        if (bfdest) *(short8v*)(Csplit + (size_t)arow * 128 + ch * 8) = v;
        else *(short8v*)((unsigned short*)Co + (size_t)arow * ldC + cbase + ch * 8) = v;
      }
    }
  } else {
    // ---- direct f32 stores (full-sector already) ----
#pragma unroll
    for (int mt = 0; mt < 4; ++mt) {
#pragma unroll
      for (int nt = 0; nt < 4; ++nt) {
        int col = bcol + wn + nt * 16 + lr;
        float bv = bias ? bias[col] : 0.f;
#pragma unroll
        for (int r4 = 0; r4 < 4; ++r4) {
          int row = brow + wm + mt * 16 + lg * 4 + r4;
          if (row < N) {
            float v = acc[mt][nt][r4] + bv;
            if (relu) v = fmaxf(v, 0.f);
            ((float*)Co)[(size_t)row * ldC + col] = v;
            if (STATS) { sc[nt] += v; scc[nt] += v * v; }
          }
        }
      }
    }
  }
  if (STATS) {
#pragma unroll
    for (int nt = 0; nt < 4; ++nt) {
      float s = sc[nt], ss = scc[nt];
      s += __shfl_xor(s, 16); s += __shfl_xor(s, 32);
      ss += __shfl_xor(ss, 16); ss += __shfl_xor(ss, 32);
      if (lg == 0) {
        int col = bcol + wn + nt * 16 + lr;
        atomicAdd(&psum[col], s);
        atomicAdd(&psqs[col], ss);
      }
    }
  }
}

// ---------------- GCN gather (CSR, bf16 rows in, f32 + bf16 out) ----------------
__global__ __launch_bounds__(256) void k_gcn_gather(const int* __restrict__ rowptr, const int* __restrict__ csr_src,
                                                    const float* __restrict__ dis,
                                                    const unsigned short* __restrict__ hp,
                                                    const float* __restrict__ bg,
                                                    float* __restrict__ c, unsigned short* __restrict__ cbf, int N) {
  int t = blockIdx.x * 256 + threadIdx.x;
  int g = t >> 5, lane = t & 31;
  if (g >= N) return;
  int off = lane << 2;
  float dd = dis[g];
  float w0 = dd * dd;
  float4 acc = *(const float4*)(bg + off);
  short4v hv = *(const short4v*)(hp + ((size_t)g << 7) + off);
  acc.x += w0 * b2f((unsigned short)hv[0]);
  acc.y += w0 * b2f((unsigned short)hv[1]);
  acc.z += w0 * b2f((unsigned short)hv[2]);
  acc.w += w0 * b2f((unsigned short)hv[3]);
  int beg = rowptr[g], end = rowptr[g + 1];
  int j = beg;
  for (; j + 3 < end; j += 4) {
    int s0 = csr_src[j], s1 = csr_src[j + 1], s2 = csr_src[j + 2], s3 = csr_src[j + 3];
    float n0 = dis[s0] * dd, n1 = dis[s1] * dd, n2 = dis[s2] * dd, n3 = dis[s3] * dd;
    short4v v0 = *(const short4v*)(hp + ((size_t)s0 << 7) + off);
    short4v v1 = *(const short4v*)(hp + ((size_t)s1 << 7) + off);
    short4v v2 = *(const short4v*)(hp + ((size_t)s2 << 7) + off);
    short4v v3 = *(const short4v*)(hp + ((size_t)s3 << 7) + off);
    acc.x += n0 * b2f((unsigned short)v0[0]) + n1 * b2f((unsigned short)v1[0]) + n2 * b2f((unsigned short)v2[0]) + n3 * b2f((unsigned short)v3[0]);
    acc.y += n0 * b2f((unsigned short)v0[1]) + n1 * b2f((unsigned short)v1[1]) + n2 * b2f((unsigned short)v2[1]) + n3 * b2f((unsigned short)v3[1]);
    acc.z += n0 * b2f((unsigned short)v0[2]) + n1 * b2f((unsigned short)v1[2]) + n2 * b2f((unsigned short)v2[2]) + n3 * b2f((unsigned short)v3[2]);
    acc.w += n0 * b2f((unsigned short)v0[3]) + n1 * b2f((unsigned short)v1[3]) + n2 * b2f((unsigned short)v2[3]) + n3 * b2f((unsigned short)v3[3]);
  }
  for (; j < end; ++j) {
    int s0 = csr_src[j];
    float n0 = dis[s0] * dd;
    short4v v0 = *(const short4v*)(hp + ((size_t)s0 << 7) + off);
    acc.x += n0 * b2f((unsigned short)v0[0]);
    acc.y += n0 * b2f((unsigned short)v0[1]);
    acc.z += n0 * b2f((unsigned short)v0[2]);
    acc.w += n0 * b2f((unsigned short)v0[3]);
  }
  *(float4*)(c + ((size_t)g << 7) + off) = acc;
  short4v b;
  b[0] = (short)f2b(acc.x); b[1] = (short)f2b(acc.y);
  b[2] = (short)f2b(acc.z); b[3] = (short)f2b(acc.w);
  *(short4v*)(cbf + ((size_t)g << 7) + off) = b;
}

// ---------------- GRU gates (bf16 gate inputs, f32 recurrent, fused BN stats) ----------------
__global__ __launch_bounds__(512) void k_gru(const unsigned short* __restrict__ gib,
                                             const unsigned short* __restrict__ ghb,
                                             float* __restrict__ cb,
                                             float* __restrict__ psum, float* __restrict__ psqs, int N) {
  int tx = threadIdx.x & 127, ty = threadIdx.x >> 7;
  int n0 = blockIdx.x * 128;
  float s = 0.f, ss = 0.f;
  for (int r = ty; r < 128; r += 4) {
    int n = n0 + r;
    if (n >= N) break;
    size_t bi = (size_t)n * 384 + tx;
    float ir = b2f(gib[bi]), iz = b2f(gib[bi + 128]), in_ = b2f(gib[bi + 256]);
    float hr = b2f(ghb[bi]), hz = b2f(ghb[bi + 128]), hn_ = b2f(ghb[bi + 256]);
    float cv = cb[(size_t)n * 128 + tx];
    float rr = 1.f / (1.f + expf(-(ir + hr)));
    float z  = 1.f / (1.f + expf(-(iz + hz)));
    float nn = tanhf(in_ + rr * hn_);
    float v = (1.f - z) * nn + z * cv;
    cb[(size_t)n * 128 + tx] = v;
    s += v; ss += v * v;
  }
  __shared__ float sd[2][4][128];
  sd[0][ty][tx] = s; sd[1][ty][tx] = ss;
  __syncthreads();
  if (ty == 0) {
    s  = sd[0][0][tx] + sd[0][1][tx] + sd[0][2][tx] + sd[0][3][tx];
    ss = sd[1][0][tx] + sd[1][1][tx] + sd[1][2][tx] + sd[1][3][tx];
    atomicAdd(&psum[tx], s);
    atomicAdd(&psqs[tx], ss);
  }
}

// ---------------- BN apply (bf16 outputs + bf16 running max) ----------------
template<int MODE, int STATS>
__global__ __launch_bounds__(512) void k_bn_apply(const float* __restrict__ x, int ldx,
                                                  const float* __restrict__ psum, const float* __restrict__ psqs,
                                                  const float* __restrict__ gamma, const float* __restrict__ beta,
                                                  float invN,
                                                  unsigned short* __restrict__ yb, unsigned short* __restrict__ mx,
                                                  float* __restrict__ npsum, float* __restrict__ npsqs,
                                                  int N, int R) {
  __shared__ float cA[128], cB[128];
  int t = threadIdx.x;
  if (t < 128) {
    float m = psum[t] * invN;
    float var = psqs[t] * invN - m * m;
    float a = gamma[t] * rsqrtf(var + EPSBN);
    cA[t] = a; cB[t] = beta[t] - m * a;
  }
  __syncthreads();
  int tx = t & 127, ty = t >> 7;
  int n0 = blockIdx.x * R;
  float s = 0.f, ss = 0.f;
  for (int r = ty; r < R; r += 4) {
    int n = n0 + r;
    if (n >= N) break;
    size_t i = (size_t)n * 128 + tx;
    float v = x[(size_t)n * ldx + tx] * cA[tx] + cB[tx];
    float w = v;
    if (MODE == 1) {
      w = fmaxf(b2f(mx[i]), v);
      mx[i] = f2b(w);
    } else {
      mx[i] = f2b(v);
    }
    yb[i] = f2b(v);
    if (STATS) { s += w; ss += w * w; }
  }
  if (STATS) {
    __shared__ float sd[2][4][128];
    sd[0][ty][tx] = s; sd[1][ty][tx] = ss;
    __syncthreads();
    if (ty == 0) {
      for (int q = 1; q < 4; ++q) { s += sd[0][q][tx]; ss += sd[1][q][tx]; }
      atomicAdd(&npsum[tx], s);
      atomicAdd(&npsqs[tx], ss);
    }
  }
}

// ---------------- BN coef ----------------
__global__ void k_coef(const float* __restrict__ psum, const float* __restrict__ psqs,
                       const float* __restrict__ gamma, const float* __restrict__ beta,
                       float invN, float* __restrict__ coef, int D) {
  int t = threadIdx.x;
  if (t < D) {
    float m = psum[t] * invN;
    float var = psqs[t] * invN - m * m;
    float a = gamma[t] * rsqrtf(var + EPSBN);
    coef[t] = a;
    coef[D + t] = beta[t] - m * a;
  }
}

// ---------------- final matvec with fused BN+relu ----------------
__global__ __launch_bounds__(256) void k_matvec(const unsigned short* __restrict__ y, const float* __restrict__ coef,
                                                const float* __restrict__ W2, const float* __restrict__ b2,
                                                float* __restrict__ out, int N) {
  int t = blockIdx.x * 256 + threadIdx.x;
  int row = t >> 6, lane = t & 63;
  if (row >= N) return;
  const unsigned short* yr = y + (size_t)row * 384;
  float s = 0.f;
#pragma unroll
  for (int k = 0; k < 4; ++k) {
    int c = lane + 64 * k;
    float v = fmaxf(b2f(yr[c]) * coef[c] + coef[256 + c], 0.f);
    s += v * W2[c];
  }
#pragma unroll
  for (int off = 32; off > 0; off >>= 1) s += __shfl_down(s, off);
  if (lane == 0) out[row] = s + b2[0];
}

// ---------------- host orchestration ----------------
extern "C" void kernel_launch(void* const* d_in, const int* in_sizes, int n_in,
                              void* d_out, int out_size, void* d_ws, size_t ws_size,
                              hipStream_t stream) {
  const float* x    = (const float*)d_in[0];
  const int*   ei   = (const int*)d_in[1];
  const float* W_in = (const float*)d_in[2];
  const float* b_in = (const float*)d_in[3];
  const float* g0   = (const float*)d_in[4];
  const float* be0  = (const float*)d_in[5];
  const float* W_g  = (const float*)d_in[6];
  const float* b_g  = (const float*)d_in[7];
  const float* W_ih = (const float*)d_in[8];
  const float* W_hh = (const float*)d_in[9];
  const float* b_ih = (const float*)d_in[10];
  const float* b_hh = (const float*)d_in[11];
  const float* g_c  = (const float*)d_in[12];
  const float* be_c = (const float*)d_in[13];
  const float* g_o  = (const float*)d_in[14];
  const float* be_o = (const float*)d_in[15];
  const float* W1   = (const float*)d_in[16];
  const float* b1   = (const float*)d_in[17];
  const float* g1   = (const float*)d_in[18];
  const float* be1  = (const float*)d_in[19];
  const float* W2   = (const float*)d_in[20];
  const float* b2   = (const float*)d_in[21];

  const int N = in_sizes[0] / 128;   // 30000
  const int E = in_sizes[1] / 2;     // 480000
  const int ND = N * 128;
  const float invN = 1.0f / (float)N;

  float* p   = (float*)d_ws;
  float* cb  = p; p += ND;               // f32: input-GEMM staging / conv out / GRU hidden
  float* dis = p; p += ((N + 255) & ~255);
  float* stats = p; p += 8 * 512;
  float* fbias = p; p += 512;
  float* coefO = p; p += 256;
  float* coef1 = p; p += 512;
  int*   degi    = (int*)p; p += ((N + 255) & ~255);
  int*   rowptr  = (int*)p; p += ((N + 1 + 255) & ~255);
  int*   cursor  = (int*)p; p += ((N + 255) & ~255);
  int*   bsum    = (int*)p; p += 256;
  int*   csr_src = (int*)p; p += E;
  unsigned short* h_bf    = (unsigned short*)p;      // [N][128] post-BN hidden
  unsigned short* hp_bf   = h_bf + (size_t)ND;       // [N][128] conv input rows
  unsigned short* cb_bf   = hp_bf + (size_t)ND;      // [N][128] conv output
  unsigned short* mx_bf   = cb_bf + (size_t)ND;      // [N][128] running max
  unsigned short* gib_bf  = mx_bf + (size_t)ND;      // [N][384] gi
  unsigned short* ghb_bf  = gib_bf + (size_t)N * 384;// [N][384] gh / y1
  unsigned short* fusedBT = ghb_bf + (size_t)N * 384;// [512][128]
  unsigned short* BThh    = fusedBT + 512 * 128;     // [384][128]
  unsigned short* BTin    = BThh + 384 * 128;        // [128][128]
  unsigned short* BT1     = BTin + 128 * 128;        // [256][128]

  float* ps0 = stats;
  float* psc[5];
  for (int i = 0; i < 5; ++i) psc[i] = stats + 512 * (1 + i);
  float* pso = stats + 512 * 6;
  float* ps1 = stats + 512 * 7;

  dim3 blk(256);
  int rb = (N + 127) / 128;
  int NBLK = (N + 255) / 256;
  int bnb = (N + 127) / 128;

  // ---- preprocessing ----
  k_wprep<<<(168448 + N + 255) / 256, blk, 0, stream>>>(W_g, W_ih, W_hh, W_in, W1, b_ih,
                                                        fusedBT, BThh, BTin, BT1, fbias, stats, degi, N);
  k_count_deg<<<(E + 255) / 256, blk, 0, stream>>>(ei + E, degi, E);
  k_scan_p1<<<NBLK, blk, 0, stream>>>(degi, rowptr, bsum, dis, N);
  k_scan_p2<<<1, blk, 0, stream>>>(bsum, NBLK);
  k_scan_p3<<<(N + 256) / 256, blk, 0, stream>>>(rowptr, cursor, bsum, N, E);
  k_csr_fill<<<(E + 255) / 256, blk, 0, stream>>>(ei, ei + E, cursor, csr_src, E);

  // ---- input layer: relu(x@W_in+b_in) -> cb (f32 ld128), stats ps0 ----
  k_mmx<0, 1, 0, 0, 0><<<dim3(1, rb), blk, 0, stream>>>(x, BTin, b_in, cb, nullptr, nullptr,
                                                        ps0, ps0 + 256, N, 128, 128, 1);
  k_bn_apply<3, 0><<<bnb, 512, 0, stream>>>(cb, 128, ps0, ps0 + 256, g0, be0, invN,
                                            h_bf, mx_bf, nullptr, nullptr, N, 128);

  for (int it = 0; it < 5; ++it) {
    // fused GEMM: col0 -> hp_bf (bf16), cols 128..511 -> gib_bf (bf16 ld384)
    k_mmx<1, 0, 1, 1, 0><<<dim3(4, rb), blk, 0, stream>>>(h_bf, fusedBT, fbias, gib_bf, hp_bf, nullptr,
                                                          nullptr, nullptr, N, 128, 384, 0);
    // GCN aggregate -> cb (f32 for GRU) + cb_bf (bf16 for GEMM2)
    k_gcn_gather<<<(N * 32 + 255) / 256, blk, 0, stream>>>(rowptr, csr_src, dis, hp_bf, b_g, cb, cb_bf, N);
    // gh = cb_bf @ W_hh^T -> ghb_bf (bf16 ld384)
    k_mmx<1, 0, 0, 1, 0><<<dim3(3, rb), blk, 0, stream>>>(cb_bf, BThh, b_hh, ghb_bf, nullptr, nullptr,
                                                          nullptr, nullptr, N, 128, 384, 0);
    // GRU gates: cb <- new hidden (in place), stats psc[it]
    k_gru<<<bnb, 512, 0, stream>>>(gib_bf, ghb_bf, cb, psc[it], psc[it] + 256, N);
    // BN + running max
    if (it < 4)
      k_bn_apply<1, 0><<<bnb, 512, 0, stream>>>(cb, 128, psc[it], psc[it] + 256, g_c, be_c, invN,
                                                h_bf, mx_bf, nullptr, nullptr, N, 128);
    else
      k_bn_apply<1, 1><<<bnb, 512, 0, stream>>>(cb, 128, psc[it], psc[it] + 256, g_c, be_c, invN,
                                                h_bf, mx_bf, pso, pso + 256, N, 128);
  }

  // ---- tail: coefO -> encoder GEMM (BN fused in staging) -> coef1 -> matvec ----
  k_coef<<<1, 128, 0, stream>>>(pso, pso + 256, g_o, be_o, invN, coefO, 128);
  k_mmx<1, 1, 0, 1, 1><<<dim3(2, rb), blk, 0, stream>>>(mx_bf, BT1, b1, ghb_bf, nullptr, coefO,
                                                        ps1, ps1 + 256, N, 128, 384, 0);
  k_coef<<<1, 256, 0, stream>>>(ps1, ps1 + 256, g1, be1, invN, coef1, 256);
  k_matvec<<<(N * 64 + 255) / 256, blk, 0, stream>>>(ghb_bf, coef1, W2, b2, (float*)d_out, N);
}

// Round 11
// 641.917 us; speedup vs baseline: 1.4993x; 1.0229x over previous
//
#include <hip/hip_runtime.h>
#include <cmath>

#define EPSBN 1e-5f

typedef __attribute__((ext_vector_type(8))) short short8v;
typedef __attribute__((ext_vector_type(4))) short short4v;
typedef __attribute__((ext_vector_type(4))) float f32x4;

__device__ inline unsigned short f2b(float x) {
  union { float f; unsigned int u; } v; v.f = x;
  unsigned int b = v.u;
  return (unsigned short)((b + 0x7FFFu + ((b >> 16) & 1u)) >> 16);
}
__device__ inline float b2f(unsigned short x) {
  union { unsigned int u; float f; } v; v.u = ((unsigned int)x) << 16;
  return v.f;
}

// ---------------- fused weight prep + zero-init ----------------
__global__ __launch_bounds__(256) void k_wprep(const float* __restrict__ W_g, const float* __restrict__ W_ih,
                                               const float* __restrict__ W_hh, const float* __restrict__ W_in,
                                               const float* __restrict__ W1, const float* __restrict__ b_ih,
                                               unsigned short* __restrict__ fusedBT, unsigned short* __restrict__ BThh,
                                               unsigned short* __restrict__ BTin, unsigned short* __restrict__ BT1,
                                               float* __restrict__ fbias, float* __restrict__ stats,
                                               int* __restrict__ degi, int N) {
  int i = blockIdx.x * 256 + threadIdx.x;
  if (i < 16384) {
    int k = i >> 7, m = i & 127;
    fusedBT[m * 128 + k] = f2b(W_g[i]);
  } else if (i < 65536) {
    int j = i - 16384;
    fusedBT[16384 + j] = f2b(W_ih[j]);
  } else if (i < 114688) {
    int j = i - 65536;
    BThh[j] = f2b(W_hh[j]);
  } else if (i < 131072) {
    int j = i - 114688;
    int k = j >> 7, m = j & 127;
    BTin[m * 128 + k] = f2b(W_in[j]);
  } else if (i < 163840) {
    int j = i - 131072;
    int k = j >> 8, m = j & 255;
    BT1[m * 128 + k] = f2b(W1[j]);
  } else if (i < 164352) {
    int j = i - 163840;
    fbias[j] = (j < 128) ? 0.f : b_ih[j - 128];
  } else if (i < 168448) {
    stats[i - 164352] = 0.f;
  } else if (i < 168448 + N) {
    degi[i - 168448] = 0;
  }
}

// ---------------- graph preprocessing ----------------
__global__ __launch_bounds__(256) void k_count_deg(const int* __restrict__ dst, int* __restrict__ deg, int E) {
  int i = blockIdx.x * 256 + threadIdx.x;
  if (i < E) atomicAdd(&deg[dst[i]], 1);
}

__global__ __launch_bounds__(256) void k_scan_p1(const int* __restrict__ deg, int* __restrict__ rowptr,
                                                 int* __restrict__ bsum, float* __restrict__ dis, int N) {
  __shared__ int sd[256];
  int t = threadIdx.x;
  int i = blockIdx.x * 256 + t;
  int v = (i < N) ? deg[i] : 0;
  if (i < N) dis[i] = rsqrtf((float)(v + 1));
  sd[t] = v;
  __syncthreads();
  for (int off = 1; off < 256; off <<= 1) {
    int u = (t >= off) ? sd[t - off] : 0;
    __syncthreads();
    sd[t] += u;
    __syncthreads();
  }
  if (i < N) rowptr[i] = sd[t] - v;
  if (t == 255) bsum[blockIdx.x] = sd[255];
}

__global__ void k_scan_p2(int* __restrict__ bsum, int NBLK) {
  __shared__ int sd[256];
  int t = threadIdx.x;
  int v = (t < NBLK) ? bsum[t] : 0;
  sd[t] = v;
  __syncthreads();
  for (int off = 1; off < 256; off <<= 1) {
    int u = (t >= off) ? sd[t - off] : 0;
    __syncthreads();
    sd[t] += u;
    __syncthreads();
  }
  if (t < NBLK) bsum[t] = sd[t] - v;
}

__global__ __launch_bounds__(256) void k_scan_p3(int* __restrict__ rowptr, int* __restrict__ cursor,
                                                 const int* __restrict__ bsum, int N, int E) {
  int i = blockIdx.x * 256 + threadIdx.x;
  if (i < N) {
    int v = rowptr[i] + bsum[blockIdx.x];
    rowptr[i] = v;
    cursor[i] = v;
  } else if (i == N) {
    rowptr[N] = E;
  }
}

__global__ __launch_bounds__(256) void k_csr_fill(const int* __restrict__ src, const int* __restrict__ dst,
                                                  int* __restrict__ cursor, int* __restrict__ csr_src, int E) {
  int e = blockIdx.x * 256 + threadIdx.x;
  if (e >= E) return;
  int s = src[e], d = dst[e];
  int pos = atomicAdd(&cursor[d], 1);
  csr_src[pos] = s;
}

// ---------------- bf16 MFMA matmul ----------------
// C = A[N,128] @ BT^T, BT is [M][128] bf16. 128x128 tile, K=128, 4 waves.
// A staged once in LDS; NCB col-blocks per block (Bs restaged per col-block;
// bf16 epilogue image goes through Bs so As survives for the next col-block).
// SPLIT: col-block 0 -> Csplit bf16 ld128; cols>=128 -> Co at col-128.
// OBF: Co is bf16. BNA: y=cA[k]*a+cB[k] during A staging (bf16 A only).
template<int ABF, int STATS, int SPLIT, int OBF, int BNA, int NCB>
__global__ __launch_bounds__(256) void k_mmx(const void* __restrict__ Ap, const unsigned short* __restrict__ BT,
                                             const float* __restrict__ bias,
                                             void* __restrict__ Co, unsigned short* __restrict__ Csplit,
                                             const float* __restrict__ coefA,
                                             float* __restrict__ psum, float* __restrict__ psqs,
                                             int N, int ldA, int ldC, int relu)
{
  __shared__ unsigned short As[128 * 128];
  __shared__ unsigned short Bs[128 * 128];
  char* Asb = (char*)As;
  char* Bsb = (char*)Bs;
  int tid = threadIdx.x;
  int brow = blockIdx.y * 128;

  // ---- stage A once ----
#pragma unroll
  for (int p = 0; p < 8; ++p) {
    int idx = p * 256 + tid;
    int r = idx >> 4, ch = idx & 15;
    int arow = brow + r;
    short8v v = {0, 0, 0, 0, 0, 0, 0, 0};
    if (ABF) {
      if (arow < N) v = *(const short8v*)((const unsigned short*)Ap + (size_t)arow * ldA + ch * 8);
      if (BNA) {
#pragma unroll
        for (int j = 0; j < 8; ++j) {
          int k = ch * 8 + j;
          float f = b2f((unsigned short)v[j]) * coefA[k] + coefA[128 + k];
          v[j] = (short)f2b(f);
        }
      }
    } else {
      if (arow < N) {
        const float* a = (const float*)Ap + (size_t)arow * ldA + ch * 8;
        f32x4 x0 = *(const f32x4*)a;
        f32x4 x1 = *(const f32x4*)(a + 4);
        v[0] = (short)f2b(x0[0]); v[1] = (short)f2b(x0[1]);
        v[2] = (short)f2b(x0[2]); v[3] = (short)f2b(x0[3]);
        v[4] = (short)f2b(x1[0]); v[5] = (short)f2b(x1[1]);
        v[6] = (short)f2b(x1[2]); v[7] = (short)f2b(x1[3]);
      }
    }
    *(short8v*)(Asb + r * 256 + ((ch * 16) ^ ((r & 7) << 4))) = v;
  }

  int w = tid >> 6, l = tid & 63;
  int wm = (w >> 1) * 64, wn = (w & 1) * 64;
  int lg = l >> 4, lr = l & 15;

  for (int cc = 0; cc < NCB; ++cc) {
    int bcol = (blockIdx.x * NCB + cc) * 128;
    if (cc > 0) __syncthreads();   // prior epilogue's Bs reads done
    // ---- stage B for this col-block ----
#pragma unroll
    for (int p = 0; p < 8; ++p) {
      int idx = p * 256 + tid;
      int r = idx >> 4, ch = idx & 15;
      short8v v = *(const short8v*)(BT + (size_t)(bcol + r) * 128 + ch * 8);
      *(short8v*)(Bsb + r * 256 + ((ch * 16) ^ ((r & 7) << 4))) = v;
    }
    __syncthreads();

    f32x4 acc[4][4] = {};
#pragma unroll
    for (int ks = 0; ks < 4; ++ks) {
      int kb = ks * 64 + lg * 8;
      short8v a[4], b[4];
#pragma unroll
      for (int mt = 0; mt < 4; ++mt) {
        int r = wm + mt * 16 + lr;
        short4v lo = *(const short4v*)(Asb + r * 256 + (kb ^ ((r & 7) << 4)));
        short4v hi = *(const short4v*)(Asb + r * 256 + ((kb + 32) ^ ((r & 7) << 4)));
        a[mt] = __builtin_shufflevector(lo, hi, 0, 1, 2, 3, 4, 5, 6, 7);
      }
#pragma unroll
      for (int nt = 0; nt < 4; ++nt) {
        int r = wn + nt * 16 + lr;
        short4v lo = *(const short4v*)(Bsb + r * 256 + (kb ^ ((r & 7) << 4)));
        short4v hi = *(const short4v*)(Bsb + r * 256 + ((kb + 32) ^ ((r & 7) << 4)));
        b[nt] = __builtin_shufflevector(lo, hi, 0, 1, 2, 3, 4, 5, 6, 7);
      }
#pragma unroll
      for (int mt = 0; mt < 4; ++mt)
#pragma unroll
        for (int nt = 0; nt < 4; ++nt)
          acc[mt][nt] = __builtin_amdgcn_mfma_f32_16x16x32_bf16(a[mt], b[nt], acc[mt][nt], 0, 0, 0);
    }

    float sc[4] = {0.f, 0.f, 0.f, 0.f}, scc[4] = {0.f, 0.f, 0.f, 0.f};
    if (OBF) {
      // ---- LDS-transposed coalesced epilogue via Bs image ----
      __syncthreads();   // MFMA reads of Bs done
#pragma unroll
      for (int mt = 0; mt < 4; ++mt) {
#pragma unroll
        for (int nt = 0; nt < 4; ++nt) {
          int colL = wn + nt * 16 + lr;
          float bv = bias ? bias[bcol + colL] : 0.f;
#pragma unroll
          for (int r4 = 0; r4 < 4; ++r4) {
            int rowL = wm + mt * 16 + lg * 4 + r4;
            float v = acc[mt][nt][r4] + bv;
            if (relu) v = fmaxf(v, 0.f);
            *(unsigned short*)(Bsb + rowL * 256 + ((colL * 2) ^ ((rowL & 7) << 4))) = f2b(v);
            if (STATS) {
              if (brow + rowL < N) { sc[nt] += v; scc[nt] += v * v; }
            }
          }
        }
      }
      __syncthreads();
      bool bfdest = SPLIT && (bcol == 0);
      int cbase = SPLIT ? (bcol - 128) : bcol;
#pragma unroll
      for (int p = 0; p < 8; ++p) {
        int idx = p * 256 + tid;
        int r = idx >> 4, ch = idx & 15;
        int arow = brow + r;
        if (arow < N) {
          short8v v = *(const short8v*)(Bsb + r * 256 + ((ch * 16) ^ ((r & 7) << 4)));
          if (bfdest) *(short8v*)(Csplit + (size_t)arow * 128 + ch * 8) = v;
          else *(short8v*)((unsigned short*)Co + (size_t)arow * ldC + cbase + ch * 8) = v;
        }
      }
    } else {
      // ---- direct f32 stores (full-sector already) ----
#pragma unroll
      for (int mt = 0; mt < 4; ++mt) {
#pragma unroll
        for (int nt = 0; nt < 4; ++nt) {
          int col = bcol + wn + nt * 16 + lr;
          float bv = bias ? bias[col] : 0.f;
#pragma unroll
          for (int r4 = 0; r4 < 4; ++r4) {
            int row = brow + wm + mt * 16 + lg * 4 + r4;
            if (row < N) {
              float v = acc[mt][nt][r4] + bv;
              if (relu) v = fmaxf(v, 0.f);
              ((float*)Co)[(size_t)row * ldC + col] = v;
              if (STATS) { sc[nt] += v; scc[nt] += v * v; }
            }
          }
        }
      }
    }
    if (STATS) {
#pragma unroll
      for (int nt = 0; nt < 4; ++nt) {
        float s = sc[nt], ss = scc[nt];
        s += __shfl_xor(s, 16); s += __shfl_xor(s, 32);
        ss += __shfl_xor(ss, 16); ss += __shfl_xor(ss, 32);
        if (lg == 0) {
          int col = bcol + wn + nt * 16 + lr;
          atomicAdd(&psum[col], s);
          atomicAdd(&psqs[col], ss);
        }
      }
    }
  }
}

// ---------------- GCN gather (CSR, bf16 rows in, f32 + bf16 out, 8x unroll) ----------------
__global__ __launch_bounds__(256) void k_gcn_gather(const int* __restrict__ rowptr, const int* __restrict__ csr_src,
                                                    const float* __restrict__ dis,
                                                    const unsigned short* __restrict__ hp,
                                                    const float* __restrict__ bg,
                                                    float* __restrict__ c, unsigned short* __restrict__ cbf, int N) {
  int t = blockIdx.x * 256 + threadIdx.x;
  int g = t >> 5, lane = t & 31;
  if (g >= N) return;
  int off = lane << 2;
  float dd = dis[g];
  float w0 = dd * dd;
  float4 acc = *(const float4*)(bg + off);
  short4v hv = *(const short4v*)(hp + ((size_t)g << 7) + off);
  acc.x += w0 * b2f((unsigned short)hv[0]);
  acc.y += w0 * b2f((unsigned short)hv[1]);
  acc.z += w0 * b2f((unsigned short)hv[2]);
  acc.w += w0 * b2f((unsigned short)hv[3]);
  int beg = rowptr[g], end = rowptr[g + 1];
  int j = beg;
  for (; j + 7 < end; j += 8) {
    int sx[8]; float nx[8]; short4v vx[8];
#pragma unroll
    for (int q = 0; q < 8; ++q) sx[q] = csr_src[j + q];
#pragma unroll
    for (int q = 0; q < 8; ++q) nx[q] = dis[sx[q]] * dd;
#pragma unroll
    for (int q = 0; q < 8; ++q) vx[q] = *(const short4v*)(hp + ((size_t)sx[q] << 7) + off);
#pragma unroll
    for (int q = 0; q < 8; ++q) {
      acc.x += nx[q] * b2f((unsigned short)vx[q][0]);
      acc.y += nx[q] * b2f((unsigned short)vx[q][1]);
      acc.z += nx[q] * b2f((unsigned short)vx[q][2]);
      acc.w += nx[q] * b2f((unsigned short)vx[q][3]);
    }
  }
  for (; j + 3 < end; j += 4) {
    int s0 = csr_src[j], s1 = csr_src[j + 1], s2 = csr_src[j + 2], s3 = csr_src[j + 3];
    float n0 = dis[s0] * dd, n1 = dis[s1] * dd, n2 = dis[s2] * dd, n3 = dis[s3] * dd;
    short4v v0 = *(const short4v*)(hp + ((size_t)s0 << 7) + off);
    short4v v1 = *(const short4v*)(hp + ((size_t)s1 << 7) + off);
    short4v v2 = *(const short4v*)(hp + ((size_t)s2 << 7) + off);
    short4v v3 = *(const short4v*)(hp + ((size_t)s3 << 7) + off);
    acc.x += n0 * b2f((unsigned short)v0[0]) + n1 * b2f((unsigned short)v1[0]) + n2 * b2f((unsigned short)v2[0]) + n3 * b2f((unsigned short)v3[0]);
    acc.y += n0 * b2f((unsigned short)v0[1]) + n1 * b2f((unsigned short)v1[1]) + n2 * b2f((unsigned short)v2[1]) + n3 * b2f((unsigned short)v3[1]);
    acc.z += n0 * b2f((unsigned short)v0[2]) + n1 * b2f((unsigned short)v1[2]) + n2 * b2f((unsigned short)v2[2]) + n3 * b2f((unsigned short)v3[2]);
    acc.w += n0 * b2f((unsigned short)v0[3]) + n1 * b2f((unsigned short)v1[3]) + n2 * b2f((unsigned short)v2[3]) + n3 * b2f((unsigned short)v3[3]);
  }
  for (; j < end; ++j) {
    int s0 = csr_src[j];
    float n0 = dis[s0] * dd;
    short4v v0 = *(const short4v*)(hp + ((size_t)s0 << 7) + off);
    acc.x += n0 * b2f((unsigned short)v0[0]);
    acc.y += n0 * b2f((unsigned short)v0[1]);
    acc.z += n0 * b2f((unsigned short)v0[2]);
    acc.w += n0 * b2f((unsigned short)v0[3]);
  }
  *(float4*)(c + ((size_t)g << 7) + off) = acc;
  short4v b;
  b[0] = (short)f2b(acc.x); b[1] = (short)f2b(acc.y);
  b[2] = (short)f2b(acc.z); b[3] = (short)f2b(acc.w);
  *(short4v*)(cbf + ((size_t)g << 7) + off) = b;
}

// ---------------- GRU gates (bf16 gate inputs, f32 recurrent, fused BN stats) ----------------
__global__ __launch_bounds__(512) void k_gru(const unsigned short* __restrict__ gib,
                                             const unsigned short* __restrict__ ghb,
                                             float* __restrict__ cb,
                                             float* __restrict__ psum, float* __restrict__ psqs, int N) {
  int tx = threadIdx.x & 127, ty = threadIdx.x >> 7;
  int n0 = blockIdx.x * 128;
  float s = 0.f, ss = 0.f;
  for (int r = ty; r < 128; r += 4) {
    int n = n0 + r;
    if (n >= N) break;
    size_t bi = (size_t)n * 384 + tx;
    float ir = b2f(gib[bi]), iz = b2f(gib[bi + 128]), in_ = b2f(gib[bi + 256]);
    float hr = b2f(ghb[bi]), hz = b2f(ghb[bi + 128]), hn_ = b2f(ghb[bi + 256]);
    float cv = cb[(size_t)n * 128 + tx];
    float rr = 1.f / (1.f + expf(-(ir + hr)));
    float z  = 1.f / (1.f + expf(-(iz + hz)));
    float nn = tanhf(in_ + rr * hn_);
    float v = (1.f - z) * nn + z * cv;
    cb[(size_t)n * 128 + tx] = v;
    s += v; ss += v * v;
  }
  __shared__ float sd[2][4][128];
  sd[0][ty][tx] = s; sd[1][ty][tx] = ss;
  __syncthreads();
  if (ty == 0) {
    s  = sd[0][0][tx] + sd[0][1][tx] + sd[0][2][tx] + sd[0][3][tx];
    ss = sd[1][0][tx] + sd[1][1][tx] + sd[1][2][tx] + sd[1][3][tx];
    atomicAdd(&psum[tx], s);
    atomicAdd(&psqs[tx], ss);
  }
}

// ---------------- BN apply (bf16 outputs + bf16 running max) ----------------
template<int MODE, int STATS>
__global__ __launch_bounds__(512) void k_bn_apply(const float* __restrict__ x, int ldx,
                                                  const float* __restrict__ psum, const float* __restrict__ psqs,
                                                  const float* __restrict__ gamma, const float* __restrict__ beta,
                                                  float invN,
                                                  unsigned short* __restrict__ yb, unsigned short* __restrict__ mx,
                                                  float* __restrict__ npsum, float* __restrict__ npsqs,
                                                  int N, int R) {
  __shared__ float cA[128], cB[128];
  int t = threadIdx.x;
  if (t < 128) {
    float m = psum[t] * invN;
    float var = psqs[t] * invN - m * m;
    float a = gamma[t] * rsqrtf(var + EPSBN);
    cA[t] = a; cB[t] = beta[t] - m * a;
  }
  __syncthreads();
  int tx = t & 127, ty = t >> 7;
  int n0 = blockIdx.x * R;
  float s = 0.f, ss = 0.f;
  for (int r = ty; r < R; r += 4) {
    int n = n0 + r;
    if (n >= N) break;
    size_t i = (size_t)n * 128 + tx;
    float v = x[(size_t)n * ldx + tx] * cA[tx] + cB[tx];
    float w = v;
    if (MODE == 1) {
      w = fmaxf(b2f(mx[i]), v);
      mx[i] = f2b(w);
    } else {
      mx[i] = f2b(v);
    }
    yb[i] = f2b(v);
    if (STATS) { s += w; ss += w * w; }
  }
  if (STATS) {
    __shared__ float sd[2][4][128];
    sd[0][ty][tx] = s; sd[1][ty][tx] = ss;
    __syncthreads();
    if (ty == 0) {
      for (int q = 1; q < 4; ++q) { s += sd[0][q][tx]; ss += sd[1][q][tx]; }
      atomicAdd(&npsum[tx], s);
      atomicAdd(&npsqs[tx], ss);
    }
  }
}

// ---------------- BN coef ----------------
__global__ void k_coef(const float* __restrict__ psum, const float* __restrict__ psqs,
                       const float* __restrict__ gamma, const float* __restrict__ beta,
                       float invN, float* __restrict__ coef, int D) {
  int t = threadIdx.x;
  if (t < D) {
    float m = psum[t] * invN;
    float var = psqs[t] * invN - m * m;
    float a = gamma[t] * rsqrtf(var + EPSBN);
    coef[t] = a;
    coef[D + t] = beta[t] - m * a;
  }
}

// ---------------- final matvec with fused BN+relu ----------------
__global__ __launch_bounds__(256) void k_matvec(const unsigned short* __restrict__ y, const float* __restrict__ coef,
                                                const float* __restrict__ W2, const float* __restrict__ b2,
                                                float* __restrict__ out, int N) {
  int t = blockIdx.x * 256 + threadIdx.x;
  int row = t >> 6, lane = t & 63;
  if (row >= N) return;
  const unsigned short* yr = y + (size_t)row * 384;
  float s = 0.f;
#pragma unroll
  for (int k = 0; k < 4; ++k) {
    int c = lane + 64 * k;
    float v = fmaxf(b2f(yr[c]) * coef[c] + coef[256 + c], 0.f);
    s += v * W2[c];
  }
#pragma unroll
  for (int off = 32; off > 0; off >>= 1) s += __shfl_down(s, off);
  if (lane == 0) out[row] = s + b2[0];
}

// ---------------- host orchestration ----------------
extern "C" void kernel_launch(void* const* d_in, const int* in_sizes, int n_in,
                              void* d_out, int out_size, void* d_ws, size_t ws_size,
                              hipStream_t stream) {
  const float* x    = (const float*)d_in[0];
  const int*   ei   = (const int*)d_in[1];
  const float* W_in = (const float*)d_in[2];
  const float* b_in = (const float*)d_in[3];
  const float* g0   = (const float*)d_in[4];
  const float* be0  = (const float*)d_in[5];
  const float* W_g  = (const float*)d_in[6];
  const float* b_g  = (const float*)d_in[7];
  const float* W_ih = (const float*)d_in[8];
  const float* W_hh = (const float*)d_in[9];
  const float* b_ih = (const float*)d_in[10];
  const float* b_hh = (const float*)d_in[11];
  const float* g_c  = (const float*)d_in[12];
  const float* be_c = (const float*)d_in[13];
  const float* g_o  = (const float*)d_in[14];
  const float* be_o = (const float*)d_in[15];
  const float* W1   = (const float*)d_in[16];
  const float* b1   = (const float*)d_in[17];
  const float* g1   = (const float*)d_in[18];
  const float* be1  = (const float*)d_in[19];
  const float* W2   = (const float*)d_in[20];
  const float* b2   = (const float*)d_in[21];

  const int N = in_sizes[0] / 128;   // 30000
  const int E = in_sizes[1] / 2;     // 480000
  const int ND = N * 128;
  const float invN = 1.0f / (float)N;

  float* p   = (float*)d_ws;
  float* cb  = p; p += ND;               // f32: input-GEMM staging / conv out / GRU hidden
  float* dis = p; p += ((N + 255) & ~255);
  float* stats = p; p += 8 * 512;
  float* fbias = p; p += 512;
  float* coefO = p; p += 256;
  float* coef1 = p; p += 512;
  int*   degi    = (int*)p; p += ((N + 255) & ~255);
  int*   rowptr  = (int*)p; p += ((N + 1 + 255) & ~255);
  int*   cursor  = (int*)p; p += ((N + 255) & ~255);
  int*   bsum    = (int*)p; p += 256;
  int*   csr_src = (int*)p; p += E;
  unsigned short* h_bf    = (unsigned short*)p;      // [N][128] post-BN hidden
  unsigned short* hp_bf   = h_bf + (size_t)ND;       // [N][128] conv input rows
  unsigned short* cb_bf   = hp_bf + (size_t)ND;      // [N][128] conv output
  unsigned short* mx_bf   = cb_bf + (size_t)ND;      // [N][128] running max
  unsigned short* gib_bf  = mx_bf + (size_t)ND;      // [N][384] gi
  unsigned short* ghb_bf  = gib_bf + (size_t)N * 384;// [N][384] gh / y1
  unsigned short* fusedBT = ghb_bf + (size_t)N * 384;// [512][128]
  unsigned short* BThh    = fusedBT + 512 * 128;     // [384][128]
  unsigned short* BTin    = BThh + 384 * 128;        // [128][128]
  unsigned short* BT1     = BTin + 128 * 128;        // [256][128]

  float* ps0 = stats;
  float* psc[5];
  for (int i = 0; i < 5; ++i) psc[i] = stats + 512 * (1 + i);
  float* pso = stats + 512 * 6;
  float* ps1 = stats + 512 * 7;

  dim3 blk(256);
  int rb = (N + 127) / 128;
  int NBLK = (N + 255) / 256;
  int bnb = (N + 127) / 128;

  // ---- preprocessing ----
  k_wprep<<<(168448 + N + 255) / 256, blk, 0, stream>>>(W_g, W_ih, W_hh, W_in, W1, b_ih,
                                                        fusedBT, BThh, BTin, BT1, fbias, stats, degi, N);
  k_count_deg<<<(E + 255) / 256, blk, 0, stream>>>(ei + E, degi, E);
  k_scan_p1<<<NBLK, blk, 0, stream>>>(degi, rowptr, bsum, dis, N);
  k_scan_p2<<<1, blk, 0, stream>>>(bsum, NBLK);
  k_scan_p3<<<(N + 256) / 256, blk, 0, stream>>>(rowptr, cursor, bsum, N, E);
  k_csr_fill<<<(E + 255) / 256, blk, 0, stream>>>(ei, ei + E, cursor, csr_src, E);

  // ---- input layer: relu(x@W_in+b_in) -> cb (f32 ld128), stats ps0 ----
  k_mmx<0, 1, 0, 0, 0, 1><<<dim3(1, rb), blk, 0, stream>>>(x, BTin, b_in, cb, nullptr, nullptr,
                                                           ps0, ps0 + 256, N, 128, 128, 1);
  k_bn_apply<3, 0><<<bnb, 512, 0, stream>>>(cb, 128, ps0, ps0 + 256, g0, be0, invN,
                                            h_bf, mx_bf, nullptr, nullptr, N, 128);

  for (int it = 0; it < 5; ++it) {
    // fused GEMM (2 col-blocks/block): col0 -> hp_bf, cols 128..511 -> gib_bf
    k_mmx<1, 0, 1, 1, 0, 2><<<dim3(2, rb), blk, 0, stream>>>(h_bf, fusedBT, fbias, gib_bf, hp_bf, nullptr,
                                                             nullptr, nullptr, N, 128, 384, 0);
    // GCN aggregate -> cb (f32 for GRU) + cb_bf (bf16 for GEMM2)
    k_gcn_gather<<<(N * 32 + 255) / 256, blk, 0, stream>>>(rowptr, csr_src, dis, hp_bf, b_g, cb, cb_bf, N);
    // gh = cb_bf @ W_hh^T -> ghb_bf (bf16 ld384)
    k_mmx<1, 0, 0, 1, 0, 1><<<dim3(3, rb), blk, 0, stream>>>(cb_bf, BThh, b_hh, ghb_bf, nullptr, nullptr,
                                                             nullptr, nullptr, N, 128, 384, 0);
    // GRU gates: cb <- new hidden (in place), stats psc[it]
    k_gru<<<bnb, 512, 0, stream>>>(gib_bf, ghb_bf, cb, psc[it], psc[it] + 256, N);
    // BN + running max
    if (it < 4)
      k_bn_apply<1, 0><<<bnb, 512, 0, stream>>>(cb, 128, psc[it], psc[it] + 256, g_c, be_c, invN,
                                                h_bf, mx_bf, nullptr, nullptr, N, 128);
    else
      k_bn_apply<1, 1><<<bnb, 512, 0, stream>>>(cb, 128, psc[it], psc[it] + 256, g_c, be_c, invN,
                                                h_bf, mx_bf, pso, pso + 256, N, 128);
  }

  // ---- tail: coefO -> encoder GEMM (BN fused in staging) -> coef1 -> matvec ----
  k_coef<<<1, 128, 0, stream>>>(pso, pso + 256, g_o, be_o, invN, coefO, 128);
  k_mmx<1, 1, 0, 1, 1, 1><<<dim3(2, rb), blk, 0, stream>>>(mx_bf, BT1, b1, ghb_bf, nullptr, coefO,
                                                           ps1, ps1 + 256, N, 128, 384, 0);
  k_coef<<<1, 256, 0, stream>>>(ps1, ps1 + 256, g1, be1, invN, coef1, 256);
  k_matvec<<<(N * 64 + 255) / 256, blk, 0, stream>>>(ghb_bf, coef1, W2, b2, (float*)d_out, N);
}